// Round 12
// baseline (445.113 us; speedup 1.0000x reference)
//
#include <hip/hip_runtime.h>
#include <hip/hip_bf16.h>

typedef __attribute__((ext_vector_type(8))) short short8;
typedef __attribute__((ext_vector_type(4))) float f32x4;

#define GLDS16(gp, lp)                                                         \
  __builtin_amdgcn_global_load_lds(                                            \
      (const __attribute__((address_space(1))) void*)(gp),                     \
      (__attribute__((address_space(3))) void*)(lp), 16, 0, 0)

static __device__ __forceinline__ unsigned int pack_bf16(float a, float b) {
  __hip_bfloat16 ba = __float2bfloat16(a), bb = __float2bfloat16(b);
  unsigned short ua = *reinterpret_cast<unsigned short*>(&ba);
  unsigned short ub = *reinterpret_cast<unsigned short*>(&bb);
  return (unsigned int)ua | ((unsigned int)ub << 16);
}

// XCD-contiguous remap of a linear block id (requires nwg % 8 == 0)
static __device__ __forceinline__ int xcd_swz(int linear, int nwg) {
  return (linear & 7) * (nwg >> 3) + (linear >> 3);
}

// ---------------- dispatch 1: cast x->bf16 + rope table + transpose(Wqa,Wkva)
__global__ __launch_bounds__(256) void cast_tr_kernel(
    const float* __restrict__ x, __hip_bfloat16* __restrict__ x_bf,
    const float* __restrict__ Wqa, const float* __restrict__ Wkva,
    __hip_bfloat16* __restrict__ WdownT,
    float* __restrict__ cs, float* __restrict__ sn)
{
  __shared__ float tile[32][33];
  int b = blockIdx.x;
  const int tid = threadIdx.x;
  if (b < 8192) {
    int i = b * 256 + tid;
    float4 v = ((const float4*)x)[i];
    x_bf[(size_t)i * 4 + 0] = __float2bfloat16(v.x);
    x_bf[(size_t)i * 4 + 1] = __float2bfloat16(v.y);
    x_bf[(size_t)i * 4 + 2] = __float2bfloat16(v.z);
    x_bf[(size_t)i * 4 + 3] = __float2bfloat16(v.w);
    if (b < 4096 && tid < 32) {
      float freq = powf(10000.f, -2.f * (float)tid / 64.f);
      float ang = (float)b * freq;
      cs[b * 32 + tid] = cosf(ang);
      sn[b * 32 + tid] = sinf(ang);
    }
    return;
  }
  b -= 8192;
  const float* in;
  __hip_bfloat16* outp;
  int K, N, Npad, gx;
  if (b < 3072) { in = Wqa;  outp = WdownT;                        K = 2048; N = 1536; Npad = 1536; gx = 48; }
  else { b -= 3072; in = Wkva; outp = WdownT + (size_t)1536 * 2048; K = 2048; N = 576;  Npad = 640;  gx = 20; }
  int n0 = (b % gx) * 32, k0 = (b / gx) * 32;
  int tx = tid & 31, ty = tid >> 5;
  #pragma unroll
  for (int i = ty; i < 32; i += 8) {
    int k = k0 + i, n = n0 + tx;
    tile[i][tx] = (n < N) ? in[(size_t)k * N + n] : 0.f;
  }
  __syncthreads();
  #pragma unroll
  for (int i = ty; i < 32; i += 8) {
    int n = n0 + i, k = k0 + tx;
    if (n < Npad) outp[(size_t)n * K + k] = __float2bfloat16(tile[tx][i]);
  }
}

// ================================================================ 128^2 GEMM core
// assumes: tid, As, Bs (bf16 ptrs), row0, col0 already defined
#define GEMM128_CORE(A, BT, Kdim)                                              \
  const int wave = tid >> 6, lane = tid & 63;                                  \
  const int wr = wave >> 1, wc = wave & 1;                                     \
  const int lq = lane & 15, grp = lane >> 4;                                   \
  const f32x4 z4 = {0.f, 0.f, 0.f, 0.f};                                       \
  f32x4 acc[4][4];                                                             \
  _Pragma("unroll") for (int i = 0; i < 4; i++)                                \
      _Pragma("unroll") for (int j = 0; j < 4; j++) acc[i][j] = z4;            \
  for (int k0 = 0; k0 < (Kdim); k0 += 32) {                                    \
    _Pragma("unroll") for (int i = 0; i < 2; i++) {                            \
      const int t = wave + 4 * i;                                              \
      const int c = t * 64 + lane;                                             \
      const int cr = c >> 2;                                                   \
      const int ko = (c & 3) << 3;                                             \
      GLDS16((A) + (size_t)(row0 + cr) * (Kdim) + (k0 + ko), (char*)As + t * 1024); \
      GLDS16((BT) + (size_t)(col0 + cr) * (Kdim) + (k0 + ko), (char*)Bs + t * 1024);\
    }                                                                          \
    __syncthreads();                                                           \
    short8 af[4], bfr[4];                                                      \
    _Pragma("unroll") for (int mm = 0; mm < 4; mm++)                           \
      af[mm] = *(const short8*)((const short*)As + ((wr * 64 + mm * 16 + lq) * 32 + grp * 8)); \
    _Pragma("unroll") for (int nn = 0; nn < 4; nn++)                           \
      bfr[nn] = *(const short8*)((const short*)Bs + ((wc * 64 + nn * 16 + lq) * 32 + grp * 8));\
    _Pragma("unroll") for (int mm = 0; mm < 4; mm++)                           \
      _Pragma("unroll") for (int nn = 0; nn < 4; nn++)                         \
        acc[mm][nn] = __builtin_amdgcn_mfma_f32_16x16x32_bf16(af[mm], bfr[nn], acc[mm][nn], 0, 0, 0); \
    __syncthreads();                                                           \
  }

// ---------------- dispatch 2: gemm_down (blocks 0..543, issued first) +
// transpose(Wqb,Wkvb,Wo) backfill (blocks 544..11295). Shared 16.5KB LDS union.
__global__ __launch_bounds__(256) void gemm_down_tr_kernel(
    const __hip_bfloat16* __restrict__ A,
    const __hip_bfloat16* __restrict__ BT,
    float* __restrict__ q_lat, float* __restrict__ kvout,
    const float* __restrict__ Wqb, const float* __restrict__ Wkvb,
    const float* __restrict__ Wo,
    __hip_bfloat16* __restrict__ WqbT, __hip_bfloat16* __restrict__ WkvbT,
    __hip_bfloat16* __restrict__ WoT)
{
  __shared__ __align__(16) char smem[16512];
  const int tid = threadIdx.x;
  int b = blockIdx.x;
  if (b < 544) {
    __hip_bfloat16* As = (__hip_bfloat16*)smem;
    __hip_bfloat16* Bs = (__hip_bfloat16*)(smem + 8192);
    const int orig = xcd_swz(b, 544);
    const int row0 = (orig / 17) * 128;
    const int col0 = (orig % 17) * 128;
    GEMM128_CORE(A, BT, 2048)
    #pragma unroll
    for (int mm = 0; mm < 4; mm++)
      #pragma unroll
      for (int nn = 0; nn < 4; nn++) {
        const int row = row0 + wr * 64 + mm * 16 + grp * 4;
        const int col = col0 + wc * 64 + nn * 16 + lq;
        float* Cp = (col < 1536) ? (q_lat + (size_t)row * 1536 + col)
                                 : (kvout + (size_t)row * 640 + (col - 1536));
        const size_t ld = (col < 1536) ? 1536 : 640;
        #pragma unroll
        for (int rr = 0; rr < 4; rr++) Cp[(size_t)rr * ld] = acc[mm][nn][rr];
      }
    return;
  }
  b -= 544;
  float (*tile)[33] = (float(*)[33])smem;
  const float* in;
  __hip_bfloat16* outp;
  int K, N, Npad, gx;
  if (b < 4608)      { in = Wqb;  outp = WqbT;  K = 1536; N = 3072; Npad = 3072; gx = 96; }
  else if (b < 6656) { b -= 4608; in = Wkvb; outp = WkvbT; K = 512;  N = 4096; Npad = 4096; gx = 128; }
  else               { b -= 6656; in = Wo;   outp = WoT;   K = 2048; N = 2048; Npad = 2048; gx = 64; }
  int n0 = (b % gx) * 32, k0 = (b / gx) * 32;
  int tx = tid & 31, ty = tid >> 5;
  #pragma unroll
  for (int i = ty; i < 32; i += 8) {
    int k = k0 + i, n = n0 + tx;
    tile[i][tx] = (n < N) ? in[(size_t)k * N + n] : 0.f;
  }
  __syncthreads();
  #pragma unroll
  for (int i = ty; i < 32; i += 8) {
    int n = n0 + i, k = k0 + tx;
    if (n < Npad) outp[(size_t)n * K + k] = __float2bfloat16(tile[tx][i]);
  }
}

// ================================================================ 256x128 GEMM core
// BM=256, BN=128, BK=64, 8 waves (4M x 2N), double-buffered 96KB LDS,
// XOR-swizzle, counted s_waitcnt vmcnt(6): next tile's 6 loads stay in flight.
// Full grids: qup 384 / kvup 512 / Wo 256 blocks (vs 192/256/128 at 256^2).
#define GEMM256x128_MAIN(Aptr, BTptr, Kdim)                                    \
  __shared__ __align__(16) char Ab[2][32768];   /* 256 rows x 128B */          \
  __shared__ __align__(16) char Bb[2][16384];   /* 128 rows x 128B */          \
  const int tid = threadIdx.x;                                                 \
  const int wid = tid >> 6, lane = tid & 63;                                   \
  const int wm = wid >> 1, wn = wid & 1;                                       \
  const int lq = lane & 15, grp = lane >> 4;                                   \
  const int nwg = gridDim.x * gridDim.y;                                       \
  const int orig = xcd_swz(blockIdx.y * gridDim.x + blockIdx.x, nwg);          \
  const int row0 = (orig / gridDim.x) * 256;                                   \
  const int col0 = (orig % gridDim.x) * 128;                                   \
  const size_t K2 = (size_t)(Kdim) * 2;                                        \
  const char* pa[4]; const char* pb[2]; int ldstA[4], ldstB[2];                \
  _Pragma("unroll") for (int i = 0; i < 4; i++) {                              \
    int L = i * 8192 + tid * 16;                                               \
    int r = L >> 7;                                                            \
    int csw = (L & 127) ^ ((r & 7) << 4);                                      \
    ldstA[i] = L;                                                              \
    pa[i] = (const char*)(Aptr) + (size_t)(row0 + r) * K2 + csw;               \
  }                                                                            \
  _Pragma("unroll") for (int i = 0; i < 2; i++) {                              \
    int L = i * 8192 + tid * 16;                                               \
    int r = L >> 7;                                                            \
    int csw = (L & 127) ^ ((r & 7) << 4);                                      \
    ldstB[i] = L;                                                              \
    pb[i] = (const char*)(BTptr) + (size_t)(col0 + r) * K2 + csw;              \
  }                                                                            \
  const int xm = (lq & 7) << 4;                                                \
  const f32x4 z4 = {0.f, 0.f, 0.f, 0.f};                                       \
  f32x4 acc[4][4];                                                             \
  _Pragma("unroll") for (int i = 0; i < 4; i++)                                \
    _Pragma("unroll") for (int j = 0; j < 4; j++) acc[i][j] = z4;              \
  const int nt = (Kdim) >> 6;                                                  \
  _Pragma("unroll") for (int i = 0; i < 4; i++) GLDS16(pa[i], &Ab[0][0] + ldstA[i]); \
  _Pragma("unroll") for (int i = 0; i < 2; i++) GLDS16(pb[i], &Bb[0][0] + ldstB[i]); \
  for (int t = 0; t < nt; ++t) {                                               \
    const int b = t & 1;                                                       \
    if (t + 1 < nt) {                                                          \
      const size_t koff = (size_t)(t + 1) * 128;                               \
      _Pragma("unroll") for (int i = 0; i < 4; i++)                            \
        GLDS16(pa[i] + koff, &Ab[b ^ 1][0] + ldstA[i]);                        \
      _Pragma("unroll") for (int i = 0; i < 2; i++)                            \
        GLDS16(pb[i] + koff, &Bb[b ^ 1][0] + ldstB[i]);                        \
      asm volatile("s_waitcnt vmcnt(6)" ::: "memory");                         \
    } else {                                                                   \
      asm volatile("s_waitcnt vmcnt(0)" ::: "memory");                         \
    }                                                                          \
    __builtin_amdgcn_sched_barrier(0);                                         \
    __builtin_amdgcn_s_barrier();                                              \
    __builtin_amdgcn_sched_barrier(0);                                         \
    const char* Ar = &Ab[b][0];                                                \
    const char* Br = &Bb[b][0];                                                \
    short8 bfr[4][2], af[4][2];                                                \
    _Pragma("unroll") for (int n = 0; n < 4; n++)                              \
      _Pragma("unroll") for (int ks = 0; ks < 2; ks++)                         \
        bfr[n][ks] = *(const short8*)(Br + (wn * 64 + n * 16 + lq) * 128 +     \
                                      ((ks * 64 + grp * 16) ^ xm));            \
    _Pragma("unroll") for (int m = 0; m < 4; m++)                              \
      _Pragma("unroll") for (int ks = 0; ks < 2; ks++)                         \
        af[m][ks] = *(const short8*)(Ar + (wm * 64 + m * 16 + lq) * 128 +      \
                                     ((ks * 64 + grp * 16) ^ xm));             \
    __builtin_amdgcn_s_setprio(1);                                             \
    _Pragma("unroll") for (int m = 0; m < 4; m++)                              \
      _Pragma("unroll") for (int n = 0; n < 4; n++)                            \
        _Pragma("unroll") for (int ks = 0; ks < 2; ks++)                       \
          acc[m][n] = __builtin_amdgcn_mfma_f32_16x16x32_bf16(                 \
              af[m][ks], bfr[n][ks], acc[m][n], 0, 0, 0);                      \
    __builtin_amdgcn_s_setprio(0);                                             \
    __builtin_amdgcn_sched_barrier(0);                                         \
    __builtin_amdgcn_s_barrier();                                              \
    __builtin_amdgcn_sched_barrier(0);                                         \
  }

// ---------------------------------------------------------------- plain 256x128 GEMM
__global__ __launch_bounds__(512, 1) void gemmw_bt_kernel(
    const __hip_bfloat16* __restrict__ A,
    const __hip_bfloat16* __restrict__ BT,
    float* __restrict__ C, int N, int K)
{
  GEMM256x128_MAIN(A, BT, K)
  #pragma unroll
  for (int m = 0; m < 4; m++)
    #pragma unroll
    for (int n = 0; n < 4; n++) {
      const int row = row0 + wm * 64 + m * 16 + grp * 4;
      const int col = col0 + wn * 64 + n * 16 + lq;
      float* Cp = C + (size_t)row * N + col;
      #pragma unroll
      for (int rr = 0; rr < 4; rr++) Cp[(size_t)rr * N] = acc[m][n][rr];
    }
}

// ------------------------------- fused Q-up GEMM (256x128): rope+scale -> Qh bf16
__global__ __launch_bounds__(512, 1) void gemmw_qup_kernel(
    const __hip_bfloat16* __restrict__ A,
    const __hip_bfloat16* __restrict__ BT,
    __hip_bfloat16* __restrict__ Qh,
    const float* __restrict__ cs_tab, const float* __restrict__ sn_tab, int K)
{
  GEMM256x128_MAIN(A, BT, K)
  const float scale = 0.10411654209f;  // (1/sqrt(192)) * log2(e)
  #pragma unroll
  for (int m = 0; m < 4; m++)
    #pragma unroll
    for (int n = 0; n < 4; n++) {
      const int col = col0 + wn * 64 + n * 16 + lq;
      const int h = col / 192;
      const int d = col - h * 192;
      const bool is_rope = (d >= 128);     // uniform per 16-col segment
      const int i = (d - 128) >> 1;
      const float sgn = (d & 1) ? 1.f : -1.f;
      #pragma unroll
      for (int rr = 0; rr < 4; rr++) {
        const int t = row0 + wm * 64 + m * 16 + grp * 4 + rr;
        float val = acc[m][n][rr];
        float partner = __shfl_xor(val, 1);
        float outv = val;
        if (is_rope) {
          float c = cs_tab[t * 32 + i];
          float s = sn_tab[t * 32 + i];
          outv = val * c + sgn * partner * s;
        }
        Qh[((size_t)h * 4096 + t) * 192 + d] = __float2bfloat16(outv * scale);
      }
    }
}

// ------------------------------- fused KV-up GEMM (256x128): K-nope + V^T
// col0 = k*128: even k -> whole block is K-nope half, odd k -> V half (uniform).
__global__ __launch_bounds__(512, 1) void gemmw_kvup_kernel(
    const __hip_bfloat16* __restrict__ A,
    const __hip_bfloat16* __restrict__ BT,
    __hip_bfloat16* __restrict__ Kh,
    __hip_bfloat16* __restrict__ Vt, int K)
{
  GEMM256x128_MAIN(A, BT, K)
  #pragma unroll
  for (int m = 0; m < 4; m++)
    #pragma unroll
    for (int n = 0; n < 4; n++) {
      const int col = col0 + wn * 64 + n * 16 + lq;
      const int h = col >> 8;
      const int j = col & 255;
      const int t0 = row0 + wm * 64 + m * 16 + grp * 4;
      if (j < 128) {
        #pragma unroll
        for (int rr = 0; rr < 4; rr++)
          Kh[((size_t)h * 4096 + t0 + rr) * 192 + j] = __float2bfloat16(acc[m][n][rr]);
      } else {
        const int vd = j - 128;
        uint2 w;
        w.x = pack_bf16(acc[m][n][0], acc[m][n][1]);
        w.y = pack_bf16(acc[m][n][2], acc[m][n][3]);
        *(uint2*)(Vt + ((size_t)h * 128 + vd) * 4096 + t0) = w;
      }
    }
}

// --------------- merged RMSNorm (q rows 0..4095, kv rows 4096..8191) + rope-K
__global__ __launch_bounds__(256) void rmsnorm2_kernel(
    const float* __restrict__ q_lat, const float* __restrict__ kv,
    const float* __restrict__ qw, const float* __restrict__ kvw,
    __hip_bfloat16* __restrict__ q_ln, __hip_bfloat16* __restrict__ kv_ln,
    const float* __restrict__ cs_tab, const float* __restrict__ sn_tab,
    __hip_bfloat16* __restrict__ Kh)
{
  const int b = blockIdx.x;
  const bool isq = (b < 4096);
  const int row = isq ? b : b - 4096;
  const int ld = isq ? 1536 : 640;
  const int W = isq ? 1536 : 512;
  const float* x = (isq ? q_lat : kv) + (size_t)row * ld;
  const float* w = isq ? qw : kvw;
  __hip_bfloat16* out = (isq ? q_ln : kv_ln) + (size_t)row * W;
  const int tid = threadIdx.x;
  const int wave = tid >> 6, lane = tid & 63;
  float ss = 0.f;
  for (int i = tid; i < W; i += 256) { float v = x[i]; ss += v * v; }
  #pragma unroll
  for (int o = 32; o; o >>= 1) ss += __shfl_xor(ss, o);
  __shared__ float red[4];
  __shared__ float stot;
  if (lane == 0) red[wave] = ss;
  __syncthreads();
  if (tid == 0) stot = red[0] + red[1] + red[2] + red[3];
  __syncthreads();
  const float rstd = rsqrtf(stot / (float)W + 1.1920929e-7f);
  for (int i = tid; i < W; i += 256)
    out[i] = __float2bfloat16(x[i] * rstd * w[i]);
  if (!isq) {
    const int t = row;
    for (int e = tid; e < 512; e += 256) {
      int h = e >> 5, i = e & 31;
      float c = cs_tab[t * 32 + i], s = sn_tab[t * 32 + i];
      float xe = x[512 + 2 * i];
      float xo = x[512 + 2 * i + 1];
      size_t base = ((size_t)h * 4096 + t) * 192 + 128 + 2 * i;
      Kh[base]     = __float2bfloat16(xe * c - xo * s);
      Kh[base + 1] = __float2bfloat16(xo * c + xe * s);
    }
  }
}

// ---------------------------------------------------------------- flash attention
// (unchanged from round 10/11: K+V LDS double-buffered, pair-balanced,
// head-grouped per XCD, permuted-K zero-shuffle P->PV, exp2 softmax,
// defer-max, deferred lsum reduce, setprio on MFMA clusters)
__global__ __launch_bounds__(256, 2) void flash_attn_kernel(
    const __hip_bfloat16* __restrict__ Qh,
    const __hip_bfloat16* __restrict__ Kh,
    const __hip_bfloat16* __restrict__ Vt,
    __hip_bfloat16* __restrict__ Obf)
{
  __shared__ __align__(16) char Klds[2][24576];   // 64 keys x 384B, swizzled
  __shared__ __align__(16) char Vlds[2][16384];   // 128 vd x 128B, swizzled

  const int hw = blockIdx.x;
  const int rest = hw >> 3;
  const int h = (hw & 7) + 8 * (rest & 1);
  const int p = rest >> 1;                        // pair index 0..31

  const int wave = threadIdx.x >> 6;
  const int lane = threadIdx.x & 63;
  const int lq = lane & 15;
  const int grp = lane >> 4;
  const int qb_[2] = {(63 - p) * 64 + wave * 16,  // f=0: heavy rows
                      p * 64 + wave * 16};        // f=1: light rows
  const int kendA = qb_[0] + 16;
  const int kendB = qb_[1] + 16;
  const int nt = 64 - p;

  const char* Kh_ = (const char*)(Kh + (size_t)h * 4096 * 192);
  const char* Vh_ = (const char*)(Vt + (size_t)h * 128 * 4096);
  const short* Qh_ = (const short*)Qh + (size_t)h * 4096 * 192;

  int kbase[6], vbase[4];
  #pragma unroll
  for (int i = 0; i < 6; i++) {
    int L = (wave * 6 + i) * 1024 + lane * 16;
    int r = L / 384, c = L - r * 384;
    int swb = (r & 3) | (((r >> 3) & 1) << 2);
    kbase[i] = r * 384 + (c ^ (swb << 4));
  }
  #pragma unroll
  for (int i = 0; i < 4; i++) {
    int L = (wave * 4 + i) * 1024 + lane * 16;
    int r = L >> 7, c = L & 127;
    vbase[i] = r * 8192 + (c ^ ((r & 7) << 4));
  }

  short8 qf[2][6];
  #pragma unroll
  for (int f = 0; f < 2; f++)
    #pragma unroll
    for (int d = 0; d < 6; d++)
      qf[f][d] = *(const short8*)(Qh_ + (size_t)(qb_[f] + lq) * 192 + d * 32 + grp * 8);

  const f32x4 z4 = {0.f, 0.f, 0.f, 0.f};
  f32x4 o_acc[2][8];
  #pragma unroll
  for (int f = 0; f < 2; f++)
    #pragma unroll
    for (int v = 0; v < 8; v++) o_acc[f][v] = z4;
  float m[2] = {-1e30f, -1e30f};
  float lsum[2] = {0.f, 0.f};

  const int krow_l = ((lq >> 2) << 3) + (lq & 3);            // + h2*32 + kt*4
  const int kxm = ((lq & 3) | (((lq >> 2) & 1) << 2)) << 4;  // K swizzle mask
  const int vxm = (lq & 7) << 4;                             // V swizzle mask

  // stage tile 0
  {
    #pragma unroll
    for (int i = 0; i < 6; i++) GLDS16(Kh_ + kbase[i], Klds[0] + (wave * 6 + i) * 1024);
    #pragma unroll
    for (int i = 0; i < 4; i++) GLDS16(Vh_ + vbase[i], Vlds[0] + (wave * 4 + i) * 1024);
  }

  for (int t = 0; t < nt; t++) {
    __syncthreads();  // stage t complete for all waves
    if (t + 1 < nt) {
      const char* Kp = Kh_ + (size_t)(t + 1) * 64 * 384;
      const char* Vp = Vh_ + (size_t)(t + 1) * 128;
      char* Kd = Klds[(t + 1) & 1];
      char* Vd = Vlds[(t + 1) & 1];
      #pragma unroll
      for (int i = 0; i < 6; i++) GLDS16(Kp + kbase[i], Kd + (wave * 6 + i) * 1024);
      #pragma unroll
      for (int i = 0; i < 4; i++) GLDS16(Vp + vbase[i], Vd + (wave * 4 + i) * 1024);
    }
    const char* Kb = Klds[t & 1];
    const char* Vb = Vlds[t & 1];
    const int ks = t * 64;

    #pragma unroll
    for (int h2 = 0; h2 < 2; h2++) {
      const int ks32 = ks + h2 * 32;
      if (ks32 >= kendA) continue;          // wave-uniform
      const bool act1 = (ks32 < kendB);     // wave-uniform

      f32x4 st[2][2];  // [f][kt]
      #pragma unroll
      for (int kt = 0; kt < 2; kt++) {
        const int row = h2 * 32 + krow_l + kt * 4;
        short8 kf[6];
        #pragma unroll
        for (int d = 0; d < 6; d++)
          kf[d] = *(const short8*)(Kb + row * 384 + ((d * 64 + grp * 16) ^ kxm));
        __builtin_amdgcn_s_setprio(1);
        #pragma unroll
        for (int f = 0; f < 2; f++) {
          if (f == 1 && !act1) continue;
          f32x4 acc = z4;
          #pragma unroll
          for (int d = 0; d < 6; d++)
            acc = __builtin_amdgcn_mfma_f32_16x16x32_bf16(kf[d], qf[f][d], acc, 0, 0, 0);
          st[f][kt] = acc;
        }
        __builtin_amdgcn_s_setprio(0);
      }

      short8 vf[8];
      #pragma unroll
      for (int v = 0; v < 8; v++)
        vf[v] = *(const short8*)(Vb + (v * 16 + lq) * 128 + ((h2 * 64 + grp * 16) ^ vxm));

      #pragma unroll
      for (int f = 0; f < 2; f++) {
        if (f == 1 && !act1) continue;
        const int qg = qb_[f] + lq;
        const bool need_mask = (ks32 + 31 > qb_[f]);
        if (need_mask) {
          #pragma unroll
          for (int kt = 0; kt < 2; kt++)
            #pragma unroll
            for (int r = 0; r < 4; r++) {
              int key = ks32 + grp * 8 + kt * 4 + r;
              if (key > qg) st[f][kt][r] = -1e30f;
            }
        }
        float tmax = fmaxf(fmaxf(fmaxf(st[f][0][0], st[f][0][1]), fmaxf(st[f][0][2], st[f][0][3])),
                           fmaxf(fmaxf(st[f][1][0], st[f][1][1]), fmaxf(st[f][1][2], st[f][1][3])));
        tmax = fmaxf(tmax, __shfl_xor(tmax, 16));
        tmax = fmaxf(tmax, __shfl_xor(tmax, 32));
        if (!__all(tmax <= m[f] + 11.5416f)) {   // 8 * log2(e)
          float mnew = fmaxf(m[f], tmax);
          float alpha = exp2f(m[f] - mnew);
          m[f] = mnew;
          lsum[f] *= alpha;
          float a0 = __shfl(alpha, grp * 4 + 0);
          float a1 = __shfl(alpha, grp * 4 + 1);
          float a2 = __shfl(alpha, grp * 4 + 2);
          float a3 = __shfl(alpha, grp * 4 + 3);
          #pragma unroll
          for (int v = 0; v < 8; v++) {
            o_acc[f][v][0] *= a0; o_acc[f][v][1] *= a1;
            o_acc[f][v][2] *= a2; o_acc[f][v][3] *= a3;
          }
        }
        float p00 = exp2f(st[f][0][0] - m[f]), p01 = exp2f(st[f][0][1] - m[f]);
        float p02 = exp2f(st[f][0][2] - m[f]), p03 = exp2f(st[f][0][3] - m[f]);
        float p10 = exp2f(st[f][1][0] - m[f]), p11 = exp2f(st[f][1][1] - m[f]);
        float p12 = exp2f(st[f][1][2] - m[f]), p13 = exp2f(st[f][1][3] - m[f]);
        lsum[f] += ((p00 + p01) + (p02 + p03)) + ((p10 + p11) + (p12 + p13));
        union { unsigned int u[4]; short8 s8; } pu;
        pu.u[0] = pack_bf16(p00, p01);
        pu.u[1] = pack_bf16(p02, p03);
        pu.u[2] = pack_bf16(p10, p11);
        pu.u[3] = pack_bf16(p12, p13);
        short8 pa = pu.s8;
        __builtin_amdgcn_s_setprio(1);
        #pragma unroll
        for (int v = 0; v < 8; v++)
          o_acc[f][v] = __builtin_amdgcn_mfma_f32_16x16x32_bf16(pa, vf[v], o_acc[f][v], 0, 0, 0);
        __builtin_amdgcn_s_setprio(0);
      }
    }
  }

  #pragma unroll
  for (int f = 0; f < 2; f++) {
    float ls = lsum[f];
    ls += __shfl_xor(ls, 16);
    ls += __shfl_xor(ls, 32);
    float linv = 1.f / ls;
    float l0 = __shfl(linv, grp * 4 + 0);
    float l1 = __shfl(linv, grp * 4 + 1);
    float l2 = __shfl(linv, grp * 4 + 2);
    float l3 = __shfl(linv, grp * 4 + 3);
    const int qb = qb_[f];
    #pragma unroll
    for (int v = 0; v < 8; v++) {
      int col = h * 128 + v * 16 + lq;
      Obf[(size_t)(qb + grp * 4 + 0) * 2048 + col] = __float2bfloat16(o_acc[f][v][0] * l0);
      Obf[(size_t)(qb + grp * 4 + 1) * 2048 + col] = __float2bfloat16(o_acc[f][v][1] * l1);
      Obf[(size_t)(qb + grp * 4 + 2) * 2048 + col] = __float2bfloat16(o_acc[f][v][2] * l2);
      Obf[(size_t)(qb + grp * 4 + 3) * 2048 + col] = __float2bfloat16(o_acc[f][v][3] * l3);
    }
  }
}

// ================================================================ launch
extern "C" void kernel_launch(void* const* d_in, const int* in_sizes, int n_in,
                              void* d_out, int out_size, void* d_ws, size_t ws_size,
                              hipStream_t stream)
{
  (void)in_sizes; (void)n_in; (void)out_size; (void)ws_size;
  const float* x     = (const float*)d_in[0];
  const float* Wqa   = (const float*)d_in[1];
  const float* qlnw  = (const float*)d_in[2];
  const float* Wqb   = (const float*)d_in[3];
  const float* Wkva  = (const float*)d_in[4];
  const float* kvlnw = (const float*)d_in[5];
  const float* Wkvb  = (const float*)d_in[6];
  const float* Wo    = (const float*)d_in[7];
  float* out = (float*)d_out;
  char* ws = (char*)d_ws;

  size_t off = 0;
  auto take = [&](size_t bytes) {
    char* p = ws + off;
    off += (bytes + 255) & ~(size_t)255;
    return p;
  };

  __hip_bfloat16* x_bf   = (__hip_bfloat16*)take((size_t)4096 * 2048 * 2);
  __hip_bfloat16* WdownT = (__hip_bfloat16*)take((size_t)2176 * 2048 * 2);  // [WqaT;WkvaT]
  __hip_bfloat16* WqbT   = (__hip_bfloat16*)take((size_t)3072 * 1536 * 2);
  __hip_bfloat16* WkvbT  = (__hip_bfloat16*)take((size_t)4096 * 512 * 2);
  __hip_bfloat16* WoT    = (__hip_bfloat16*)take((size_t)2048 * 2048 * 2);
  char* regA             = take((size_t)4096 * 1536 * 4);  // q_lat (f32) -> Qh (bf16)
  float* kv              = (float*)take((size_t)4096 * 640 * 4);
  __hip_bfloat16* q_ln   = (__hip_bfloat16*)take((size_t)4096 * 1536 * 2);
  __hip_bfloat16* kv_ln  = (__hip_bfloat16*)take((size_t)4096 * 512 * 2);
  float* cs_tab          = (float*)take((size_t)4096 * 32 * 4);
  float* sn_tab          = (float*)take((size_t)4096 * 32 * 4);
  __hip_bfloat16* Khp    = (__hip_bfloat16*)take((size_t)16 * 4096 * 192 * 2);
  __hip_bfloat16* Vtp    = (__hip_bfloat16*)take((size_t)16 * 128 * 4096 * 2);
  __hip_bfloat16* o_bf   = (__hip_bfloat16*)take((size_t)4096 * 2048 * 2);

  float* q_lat = (float*)regA;
  __hip_bfloat16* Qh = (__hip_bfloat16*)regA;   // reuse after rmsnorm consumes q_lat

  // 1. cast x + rope table + transpose(Wqa,Wkva)
  cast_tr_kernel<<<dim3(12544), 256, 0, stream>>>(x, x_bf, Wqa, Wkva, WdownT,
                                                  cs_tab, sn_tab);

  // 2. gemm_down (first 544 blocks) + transpose(Wqb,Wkvb,Wo) backfill
  gemm_down_tr_kernel<<<dim3(11296), 256, 0, stream>>>(
      x_bf, WdownT, q_lat, kv, Wqb, Wkvb, Wo, WqbT, WkvbT, WoT);

  // 3. merged norms + rope-K broadcast
  rmsnorm2_kernel<<<dim3(8192), 256, 0, stream>>>(q_lat, kv, qlnw, kvlnw, q_ln, kv_ln,
                                                  cs_tab, sn_tab, Khp);

  // 4. fused up-projections (256x128 tiles, full grids: 384 / 512 blocks)
  gemmw_qup_kernel<<<dim3(24, 16), 512, 0, stream>>>(q_ln, WqbT, Qh, cs_tab, sn_tab, 1536);
  gemmw_kvup_kernel<<<dim3(32, 16), 512, 0, stream>>>(kv_ln, WkvbT, Khp, Vtp, 512);

  // 5. attention (pair-balanced, head-grouped per XCD, K+V LDS double-buffered)
  flash_attn_kernel<<<dim3(512), 256, 0, stream>>>(Qh, Khp, Vtp, o_bf);

  // 6. output projection (256x128 tiles, 256 blocks = 1/CU) -> d_out (f32)
  gemmw_bt_kernel<<<dim3(16, 16), 512, 0, stream>>>(o_bf, WoT, out, 2048, 2048);
}

// Round 13
// 427.153 us; speedup vs baseline: 1.0420x; 1.0420x over previous
//
#include <hip/hip_runtime.h>
#include <hip/hip_bf16.h>

typedef __attribute__((ext_vector_type(8))) short short8;
typedef __attribute__((ext_vector_type(4))) float f32x4;

#define GLDS16(gp, lp)                                                         \
  __builtin_amdgcn_global_load_lds(                                            \
      (const __attribute__((address_space(1))) void*)(gp),                     \
      (__attribute__((address_space(3))) void*)(lp), 16, 0, 0)

static __device__ __forceinline__ unsigned int pack_bf16(float a, float b) {
  __hip_bfloat16 ba = __float2bfloat16(a), bb = __float2bfloat16(b);
  unsigned short ua = *reinterpret_cast<unsigned short*>(&ba);
  unsigned short ub = *reinterpret_cast<unsigned short*>(&bb);
  return (unsigned int)ua | ((unsigned int)ub << 16);
}

// XCD-contiguous remap of a linear block id (requires nwg % 8 == 0)
static __device__ __forceinline__ int xcd_swz(int linear, int nwg) {
  return (linear & 7) * (nwg >> 3) + (linear >> 3);
}

// ---------------- dispatch 1: cast x->bf16 + rope table + transpose(Wqa,Wkva)
__global__ __launch_bounds__(256) void cast_tr_kernel(
    const float* __restrict__ x, __hip_bfloat16* __restrict__ x_bf,
    const float* __restrict__ Wqa, const float* __restrict__ Wkva,
    __hip_bfloat16* __restrict__ WdownT,
    float* __restrict__ cs, float* __restrict__ sn)
{
  __shared__ float tile[32][33];
  int b = blockIdx.x;
  const int tid = threadIdx.x;
  if (b < 8192) {
    int i = b * 256 + tid;
    float4 v = ((const float4*)x)[i];
    x_bf[(size_t)i * 4 + 0] = __float2bfloat16(v.x);
    x_bf[(size_t)i * 4 + 1] = __float2bfloat16(v.y);
    x_bf[(size_t)i * 4 + 2] = __float2bfloat16(v.z);
    x_bf[(size_t)i * 4 + 3] = __float2bfloat16(v.w);
    if (b < 4096 && tid < 32) {
      float freq = powf(10000.f, -2.f * (float)tid / 64.f);
      float ang = (float)b * freq;
      cs[b * 32 + tid] = cosf(ang);
      sn[b * 32 + tid] = sinf(ang);
    }
    return;
  }
  b -= 8192;
  const float* in;
  __hip_bfloat16* outp;
  int K, N, Npad, gx;
  if (b < 3072) { in = Wqa;  outp = WdownT;                        K = 2048; N = 1536; Npad = 1536; gx = 48; }
  else { b -= 3072; in = Wkva; outp = WdownT + (size_t)1536 * 2048; K = 2048; N = 576;  Npad = 640;  gx = 20; }
  int n0 = (b % gx) * 32, k0 = (b / gx) * 32;
  int tx = tid & 31, ty = tid >> 5;
  #pragma unroll
  for (int i = ty; i < 32; i += 8) {
    int k = k0 + i, n = n0 + tx;
    tile[i][tx] = (n < N) ? in[(size_t)k * N + n] : 0.f;
  }
  __syncthreads();
  #pragma unroll
  for (int i = ty; i < 32; i += 8) {
    int n = n0 + i, k = k0 + tx;
    if (n < Npad) outp[(size_t)n * K + k] = __float2bfloat16(tile[tx][i]);
  }
}

// ================================================================ 128^2 GEMM core
// assumes: tid, As, Bs (bf16 ptrs), row0, col0 already defined
#define GEMM128_CORE(A, BT, Kdim)                                              \
  const int wave = tid >> 6, lane = tid & 63;                                  \
  const int wr = wave >> 1, wc = wave & 1;                                     \
  const int lq = lane & 15, grp = lane >> 4;                                   \
  const f32x4 z4 = {0.f, 0.f, 0.f, 0.f};                                       \
  f32x4 acc[4][4];                                                             \
  _Pragma("unroll") for (int i = 0; i < 4; i++)                                \
      _Pragma("unroll") for (int j = 0; j < 4; j++) acc[i][j] = z4;            \
  for (int k0 = 0; k0 < (Kdim); k0 += 32) {                                    \
    _Pragma("unroll") for (int i = 0; i < 2; i++) {                            \
      const int t = wave + 4 * i;                                              \
      const int c = t * 64 + lane;                                             \
      const int cr = c >> 2;                                                   \
      const int ko = (c & 3) << 3;                                             \
      GLDS16((A) + (size_t)(row0 + cr) * (Kdim) + (k0 + ko), (char*)As + t * 1024); \
      GLDS16((BT) + (size_t)(col0 + cr) * (Kdim) + (k0 + ko), (char*)Bs + t * 1024);\
    }                                                                          \
    __syncthreads();                                                           \
    short8 af[4], bfr[4];                                                      \
    _Pragma("unroll") for (int mm = 0; mm < 4; mm++)                           \
      af[mm] = *(const short8*)((const short*)As + ((wr * 64 + mm * 16 + lq) * 32 + grp * 8)); \
    _Pragma("unroll") for (int nn = 0; nn < 4; nn++)                           \
      bfr[nn] = *(const short8*)((const short*)Bs + ((wc * 64 + nn * 16 + lq) * 32 + grp * 8));\
    _Pragma("unroll") for (int mm = 0; mm < 4; mm++)                           \
      _Pragma("unroll") for (int nn = 0; nn < 4; nn++)                         \
        acc[mm][nn] = __builtin_amdgcn_mfma_f32_16x16x32_bf16(af[mm], bfr[nn], acc[mm][nn], 0, 0, 0); \
    __syncthreads();                                                           \
  }

// ---------------------------------------------------------------- plain 128^2 GEMM
__global__ __launch_bounds__(256) void gemm_bt_kernel(
    const __hip_bfloat16* __restrict__ A,
    const __hip_bfloat16* __restrict__ BT,
    float* __restrict__ C, int M, int N, int K)
{
  __shared__ __hip_bfloat16 As[128 * 32];
  __shared__ __hip_bfloat16 Bs[128 * 32];
  const int tid = threadIdx.x;
  const int nwg = gridDim.x * gridDim.y;
  const int orig = xcd_swz(blockIdx.y * gridDim.x + blockIdx.x, nwg);
  const int row0 = (orig / gridDim.x) * 128;
  const int col0 = (orig % gridDim.x) * 128;
  GEMM128_CORE(A, BT, K)
  (void)M;
  #pragma unroll
  for (int mm = 0; mm < 4; mm++)
    #pragma unroll
    for (int nn = 0; nn < 4; nn++) {
      const int row = row0 + wr * 64 + mm * 16 + grp * 4;
      const int col = col0 + wc * 64 + nn * 16 + lq;
      float* Cp = C + (size_t)row * N + col;
      #pragma unroll
      for (int rr = 0; rr < 4; rr++) Cp[(size_t)rr * N] = acc[mm][nn][rr];
    }
}

// ---------------- dispatch 2: gemm_down (blocks 0..543, issued first) +
// transpose(Wqb,Wkvb,Wo) backfill (blocks 544..11295). Shared 16.5KB LDS union.
__global__ __launch_bounds__(256) void gemm_down_tr_kernel(
    const __hip_bfloat16* __restrict__ A,
    const __hip_bfloat16* __restrict__ BT,
    float* __restrict__ q_lat, float* __restrict__ kvout,
    const float* __restrict__ Wqb, const float* __restrict__ Wkvb,
    const float* __restrict__ Wo,
    __hip_bfloat16* __restrict__ WqbT, __hip_bfloat16* __restrict__ WkvbT,
    __hip_bfloat16* __restrict__ WoT)
{
  __shared__ __align__(16) char smem[16512];
  const int tid = threadIdx.x;
  int b = blockIdx.x;
  if (b < 544) {
    __hip_bfloat16* As = (__hip_bfloat16*)smem;
    __hip_bfloat16* Bs = (__hip_bfloat16*)(smem + 8192);
    const int orig = xcd_swz(b, 544);
    const int row0 = (orig / 17) * 128;
    const int col0 = (orig % 17) * 128;
    GEMM128_CORE(A, BT, 2048)
    #pragma unroll
    for (int mm = 0; mm < 4; mm++)
      #pragma unroll
      for (int nn = 0; nn < 4; nn++) {
        const int row = row0 + wr * 64 + mm * 16 + grp * 4;
        const int col = col0 + wc * 64 + nn * 16 + lq;
        float* Cp = (col < 1536) ? (q_lat + (size_t)row * 1536 + col)
                                 : (kvout + (size_t)row * 640 + (col - 1536));
        const size_t ld = (col < 1536) ? 1536 : 640;
        #pragma unroll
        for (int rr = 0; rr < 4; rr++) Cp[(size_t)rr * ld] = acc[mm][nn][rr];
      }
    return;
  }
  b -= 544;
  float (*tile)[33] = (float(*)[33])smem;
  const float* in;
  __hip_bfloat16* outp;
  int K, N, Npad, gx;
  if (b < 4608)      { in = Wqb;  outp = WqbT;  K = 1536; N = 3072; Npad = 3072; gx = 96; }
  else if (b < 6656) { b -= 4608; in = Wkvb; outp = WkvbT; K = 512;  N = 4096; Npad = 4096; gx = 128; }
  else               { b -= 6656; in = Wo;   outp = WoT;   K = 2048; N = 2048; Npad = 2048; gx = 64; }
  int n0 = (b % gx) * 32, k0 = (b / gx) * 32;
  int tx = tid & 31, ty = tid >> 5;
  #pragma unroll
  for (int i = ty; i < 32; i += 8) {
    int k = k0 + i, n = n0 + tx;
    tile[i][tx] = (n < N) ? in[(size_t)k * N + n] : 0.f;
  }
  __syncthreads();
  #pragma unroll
  for (int i = ty; i < 32; i += 8) {
    int n = n0 + i, k = k0 + tx;
    if (n < Npad) outp[(size_t)n * K + k] = __float2bfloat16(tile[tx][i]);
  }
}

// ================================================================ 256^2 GEMM core
// BK=64, 8 waves, double-buffered 128KB LDS, XOR-swizzle, counted vmcnt(8).
#define GEMM256_MAIN(Aptr, BTptr, Kdim)                                        \
  __shared__ __align__(16) char Ab[2][32768];                                  \
  __shared__ __align__(16) char Bb[2][32768];                                  \
  const int tid = threadIdx.x;                                                 \
  const int wid = tid >> 6, lane = tid & 63;                                   \
  const int wm = wid >> 2, wn = wid & 3;                                       \
  const int lq = lane & 15, grp = lane >> 4;                                   \
  const int nwg = gridDim.x * gridDim.y;                                       \
  const int orig = xcd_swz(blockIdx.y * gridDim.x + blockIdx.x, nwg);          \
  const int row0 = (orig / gridDim.x) * 256;                                   \
  const int col0 = (orig % gridDim.x) * 256;                                   \
  const size_t K2 = (size_t)(Kdim) * 2;                                        \
  const char* pa[4]; const char* pb[4]; int ldst[4];                           \
  _Pragma("unroll") for (int i = 0; i < 4; i++) {                              \
    int L = i * 8192 + tid * 16;                                               \
    int r = L >> 7;                                                            \
    int csw = (L & 127) ^ ((r & 7) << 4);                                      \
    ldst[i] = L;                                                               \
    pa[i] = (const char*)(Aptr) + (size_t)(row0 + r) * K2 + csw;               \
    pb[i] = (const char*)(BTptr) + (size_t)(col0 + r) * K2 + csw;              \
  }                                                                            \
  const int xm = (lq & 7) << 4;                                                \
  const f32x4 z4 = {0.f, 0.f, 0.f, 0.f};                                       \
  f32x4 acc[8][4];                                                             \
  _Pragma("unroll") for (int i = 0; i < 8; i++)                                \
    _Pragma("unroll") for (int j = 0; j < 4; j++) acc[i][j] = z4;              \
  const int nt = (Kdim) >> 6;                                                  \
  _Pragma("unroll") for (int i = 0; i < 4; i++) {                              \
    GLDS16(pa[i], &Ab[0][0] + ldst[i]);                                        \
    GLDS16(pb[i], &Bb[0][0] + ldst[i]);                                        \
  }                                                                            \
  for (int t = 0; t < nt; ++t) {                                               \
    const int b = t & 1;                                                       \
    if (t + 1 < nt) {                                                          \
      const size_t koff = (size_t)(t + 1) * 128;                               \
      _Pragma("unroll") for (int i = 0; i < 4; i++) {                          \
        GLDS16(pa[i] + koff, &Ab[b ^ 1][0] + ldst[i]);                         \
        GLDS16(pb[i] + koff, &Bb[b ^ 1][0] + ldst[i]);                         \
      }                                                                        \
      asm volatile("s_waitcnt vmcnt(8)" ::: "memory");                         \
    } else {                                                                   \
      asm volatile("s_waitcnt vmcnt(0)" ::: "memory");                         \
    }                                                                          \
    __builtin_amdgcn_sched_barrier(0);                                         \
    __builtin_amdgcn_s_barrier();                                              \
    __builtin_amdgcn_sched_barrier(0);                                         \
    const char* Ar = &Ab[b][0];                                                \
    const char* Br = &Bb[b][0];                                                \
    short8 bfr[4][2];                                                          \
    _Pragma("unroll") for (int n = 0; n < 4; n++)                              \
      _Pragma("unroll") for (int ks = 0; ks < 2; ks++)                         \
        bfr[n][ks] = *(const short8*)(Br + (wn * 64 + n * 16 + lq) * 128 +     \
                                      ((ks * 64 + grp * 16) ^ xm));            \
    _Pragma("unroll") for (int mh = 0; mh < 4; mh++) {                         \
      short8 af[2][2];                                                         \
      _Pragma("unroll") for (int mi = 0; mi < 2; mi++)                         \
        _Pragma("unroll") for (int ks = 0; ks < 2; ks++)                       \
          af[mi][ks] = *(const short8*)(Ar + (wm * 128 + (mh * 2 + mi) * 16 + lq) * 128 + \
                                        ((ks * 64 + grp * 16) ^ xm));          \
      __builtin_amdgcn_s_setprio(1);                                           \
      _Pragma("unroll") for (int mi = 0; mi < 2; mi++)                         \
        _Pragma("unroll") for (int n = 0; n < 4; n++)                          \
          _Pragma("unroll") for (int ks = 0; ks < 2; ks++)                     \
            acc[mh * 2 + mi][n] = __builtin_amdgcn_mfma_f32_16x16x32_bf16(     \
                af[mi][ks], bfr[n][ks], acc[mh * 2 + mi][n], 0, 0, 0);         \
      __builtin_amdgcn_s_setprio(0);                                           \
    }                                                                          \
    __builtin_amdgcn_sched_barrier(0);                                         \
    __builtin_amdgcn_s_barrier();                                              \
    __builtin_amdgcn_sched_barrier(0);                                         \
  }

// ------------------------------- fused Q-up GEMM (256^2): rope+scale -> Qh bf16
__global__ __launch_bounds__(512, 2) void gemm256_qup_kernel(
    const __hip_bfloat16* __restrict__ A,
    const __hip_bfloat16* __restrict__ BT,
    __hip_bfloat16* __restrict__ Qh,
    const float* __restrict__ cs_tab, const float* __restrict__ sn_tab, int K)
{
  GEMM256_MAIN(A, BT, K)
  const float scale = 0.10411654209f;  // (1/sqrt(192)) * log2(e)
  #pragma unroll
  for (int m = 0; m < 8; m++)
    #pragma unroll
    for (int n = 0; n < 4; n++) {
      const int col = col0 + wn * 64 + n * 16 + lq;
      const int h = col / 192;
      const int d = col - h * 192;
      const bool is_rope = (d >= 128);     // uniform per 16-col segment
      const int i = (d - 128) >> 1;
      const float sgn = (d & 1) ? 1.f : -1.f;
      #pragma unroll
      for (int rr = 0; rr < 4; rr++) {
        const int t = row0 + wm * 128 + m * 16 + grp * 4 + rr;
        float val = acc[m][n][rr];
        float partner = __shfl_xor(val, 1);
        float outv = val;
        if (is_rope) {
          float c = cs_tab[t * 32 + i];
          float s = sn_tab[t * 32 + i];
          outv = val * c + sgn * partner * s;
        }
        Qh[((size_t)h * 4096 + t) * 192 + d] = __float2bfloat16(outv * scale);
      }
    }
}

// ------------------------------- fused KV-up GEMM (256^2): K-nope + V^T
__global__ __launch_bounds__(512, 2) void gemm256_kvup_kernel(
    const __hip_bfloat16* __restrict__ A,
    const __hip_bfloat16* __restrict__ BT,
    __hip_bfloat16* __restrict__ Kh,
    __hip_bfloat16* __restrict__ Vt, int K)
{
  GEMM256_MAIN(A, BT, K)
  #pragma unroll
  for (int m = 0; m < 8; m++)
    #pragma unroll
    for (int n = 0; n < 4; n++) {
      const int col = col0 + wn * 64 + n * 16 + lq;
      const int h = col >> 8;
      const int j = col & 255;
      const int t0 = row0 + wm * 128 + m * 16 + grp * 4;
      if (j < 128) {                       // uniform per 16-col segment
        #pragma unroll
        for (int rr = 0; rr < 4; rr++)
          Kh[((size_t)h * 4096 + t0 + rr) * 192 + j] = __float2bfloat16(acc[m][n][rr]);
      } else {
        const int vd = j - 128;
        uint2 w;
        w.x = pack_bf16(acc[m][n][0], acc[m][n][1]);
        w.y = pack_bf16(acc[m][n][2], acc[m][n][3]);
        *(uint2*)(Vt + ((size_t)h * 128 + vd) * 4096 + t0) = w;
      }
    }
}

// --------------- merged RMSNorm (q rows 0..4095, kv rows 4096..8191) + rope-K
__global__ __launch_bounds__(256) void rmsnorm2_kernel(
    const float* __restrict__ q_lat, const float* __restrict__ kv,
    const float* __restrict__ qw, const float* __restrict__ kvw,
    __hip_bfloat16* __restrict__ q_ln, __hip_bfloat16* __restrict__ kv_ln,
    const float* __restrict__ cs_tab, const float* __restrict__ sn_tab,
    __hip_bfloat16* __restrict__ Kh)
{
  const int b = blockIdx.x;
  const bool isq = (b < 4096);
  const int row = isq ? b : b - 4096;
  const int ld = isq ? 1536 : 640;
  const int W = isq ? 1536 : 512;
  const float* x = (isq ? q_lat : kv) + (size_t)row * ld;
  const float* w = isq ? qw : kvw;
  __hip_bfloat16* out = (isq ? q_ln : kv_ln) + (size_t)row * W;
  const int tid = threadIdx.x;
  const int wave = tid >> 6, lane = tid & 63;
  float ss = 0.f;
  for (int i = tid; i < W; i += 256) { float v = x[i]; ss += v * v; }
  #pragma unroll
  for (int o = 32; o; o >>= 1) ss += __shfl_xor(ss, o);
  __shared__ float red[4];
  __shared__ float stot;
  if (lane == 0) red[wave] = ss;
  __syncthreads();
  if (tid == 0) stot = red[0] + red[1] + red[2] + red[3];
  __syncthreads();
  const float rstd = rsqrtf(stot / (float)W + 1.1920929e-7f);
  for (int i = tid; i < W; i += 256)
    out[i] = __float2bfloat16(x[i] * rstd * w[i]);
  if (!isq) {
    const int t = row;
    for (int e = tid; e < 512; e += 256) {
      int h = e >> 5, i = e & 31;
      float c = cs_tab[t * 32 + i], s = sn_tab[t * 32 + i];
      float xe = x[512 + 2 * i];
      float xo = x[512 + 2 * i + 1];
      size_t base = ((size_t)h * 4096 + t) * 192 + 128 + 2 * i;
      Kh[base]     = __float2bfloat16(xe * c - xo * s);
      Kh[base + 1] = __float2bfloat16(xo * c + xe * s);
    }
  }
}

// ---------------------------------------------------------------- flash attention
// K+V staged in LDS (64-key tiles, double-buffered, pre-swizzled source).
// Pair-balanced causal tiling; each XCD hosts 2 heads (K/V L2-resident).
// K rows permuted at QK so P lands directly in the PV A-fragment layout.
// exp2-domain softmax; defer-max via LANE-PARTIAL __all (shuffle reduce only
// inside the rescale branch); lsum partials reduced once; setprio on MFMA.
__global__ __launch_bounds__(256, 2) void flash_attn_kernel(
    const __hip_bfloat16* __restrict__ Qh,
    const __hip_bfloat16* __restrict__ Kh,
    const __hip_bfloat16* __restrict__ Vt,
    __hip_bfloat16* __restrict__ Obf)
{
  __shared__ __align__(16) char Klds[2][24576];   // 64 keys x 384B, swizzled
  __shared__ __align__(16) char Vlds[2][16384];   // 128 vd x 128B, swizzled

  const int hw = blockIdx.x;
  const int rest = hw >> 3;
  const int h = (hw & 7) + 8 * (rest & 1);
  const int p = rest >> 1;                        // pair index 0..31

  const int wave = threadIdx.x >> 6;
  const int lane = threadIdx.x & 63;
  const int lq = lane & 15;
  const int grp = lane >> 4;
  const int qb_[2] = {(63 - p) * 64 + wave * 16,  // f=0: heavy rows
                      p * 64 + wave * 16};        // f=1: light rows
  const int kendA = qb_[0] + 16;
  const int kendB = qb_[1] + 16;
  const int nt = 64 - p;

  const char* Kh_ = (const char*)(Kh + (size_t)h * 4096 * 192);
  const char* Vh_ = (const char*)(Vt + (size_t)h * 128 * 4096);
  const short* Qh_ = (const short*)Qh + (size_t)h * 4096 * 192;

  int kbase[6], vbase[4];
  #pragma unroll
  for (int i = 0; i < 6; i++) {
    int L = (wave * 6 + i) * 1024 + lane * 16;
    int r = L / 384, c = L - r * 384;
    int swb = (r & 3) | (((r >> 3) & 1) << 2);
    kbase[i] = r * 384 + (c ^ (swb << 4));
  }
  #pragma unroll
  for (int i = 0; i < 4; i++) {
    int L = (wave * 4 + i) * 1024 + lane * 16;
    int r = L >> 7, c = L & 127;
    vbase[i] = r * 8192 + (c ^ ((r & 7) << 4));
  }

  short8 qf[2][6];
  #pragma unroll
  for (int f = 0; f < 2; f++)
    #pragma unroll
    for (int d = 0; d < 6; d++)
      qf[f][d] = *(const short8*)(Qh_ + (size_t)(qb_[f] + lq) * 192 + d * 32 + grp * 8);

  const f32x4 z4 = {0.f, 0.f, 0.f, 0.f};
  f32x4 o_acc[2][8];
  #pragma unroll
  for (int f = 0; f < 2; f++)
    #pragma unroll
    for (int v = 0; v < 8; v++) o_acc[f][v] = z4;
  float m[2] = {-1e30f, -1e30f};
  float lsum[2] = {0.f, 0.f};

  const int krow_l = ((lq >> 2) << 3) + (lq & 3);            // + h2*32 + kt*4
  const int kxm = ((lq & 3) | (((lq >> 2) & 1) << 2)) << 4;  // K swizzle mask
  const int vxm = (lq & 7) << 4;                             // V swizzle mask

  // stage tile 0
  {
    #pragma unroll
    for (int i = 0; i < 6; i++) GLDS16(Kh_ + kbase[i], Klds[0] + (wave * 6 + i) * 1024);
    #pragma unroll
    for (int i = 0; i < 4; i++) GLDS16(Vh_ + vbase[i], Vlds[0] + (wave * 4 + i) * 1024);
  }

  for (int t = 0; t < nt; t++) {
    __syncthreads();  // stage t complete for all waves
    if (t + 1 < nt) {
      const char* Kp = Kh_ + (size_t)(t + 1) * 64 * 384;
      const char* Vp = Vh_ + (size_t)(t + 1) * 128;
      char* Kd = Klds[(t + 1) & 1];
      char* Vd = Vlds[(t + 1) & 1];
      #pragma unroll
      for (int i = 0; i < 6; i++) GLDS16(Kp + kbase[i], Kd + (wave * 6 + i) * 1024);
      #pragma unroll
      for (int i = 0; i < 4; i++) GLDS16(Vp + vbase[i], Vd + (wave * 4 + i) * 1024);
    }
    const char* Kb = Klds[t & 1];
    const char* Vb = Vlds[t & 1];
    const int ks = t * 64;

    #pragma unroll
    for (int h2 = 0; h2 < 2; h2++) {
      const int ks32 = ks + h2 * 32;
      if (ks32 >= kendA) continue;          // wave-uniform
      const bool act1 = (ks32 < kendB);     // wave-uniform

      f32x4 st[2][2];  // [f][kt]
      #pragma unroll
      for (int kt = 0; kt < 2; kt++) {
        const int row = h2 * 32 + krow_l + kt * 4;
        short8 kf[6];
        #pragma unroll
        for (int d = 0; d < 6; d++)
          kf[d] = *(const short8*)(Kb + row * 384 + ((d * 64 + grp * 16) ^ kxm));
        __builtin_amdgcn_s_setprio(1);
        #pragma unroll
        for (int f = 0; f < 2; f++) {
          if (f == 1 && !act1) continue;
          f32x4 acc = z4;
          #pragma unroll
          for (int d = 0; d < 6; d++)
            acc = __builtin_amdgcn_mfma_f32_16x16x32_bf16(kf[d], qf[f][d], acc, 0, 0, 0);
          st[f][kt] = acc;
        }
        __builtin_amdgcn_s_setprio(0);
      }

      short8 vf[8];
      #pragma unroll
      for (int v = 0; v < 8; v++)
        vf[v] = *(const short8*)(Vb + (v * 16 + lq) * 128 + ((h2 * 64 + grp * 16) ^ vxm));

      #pragma unroll
      for (int f = 0; f < 2; f++) {
        if (f == 1 && !act1) continue;
        const int qg = qb_[f] + lq;
        const bool need_mask = (ks32 + 31 > qb_[f]);
        if (need_mask) {
          #pragma unroll
          for (int kt = 0; kt < 2; kt++)
            #pragma unroll
            for (int r = 0; r < 4; r++) {
              int key = ks32 + grp * 8 + kt * 4 + r;
              if (key > qg) st[f][kt][r] = -1e30f;
            }
        }
        // lane-partial defer-max: row max = max over 4 partner lanes' partials,
        // so __all(partial <= m+THR)  <=>  __all(rowmax <= m+THR). Shuffle
        // reduce only needed when the rescale actually fires.
        float tpart = fmaxf(fmaxf(fmaxf(st[f][0][0], st[f][0][1]), fmaxf(st[f][0][2], st[f][0][3])),
                            fmaxf(fmaxf(st[f][1][0], st[f][1][1]), fmaxf(st[f][1][2], st[f][1][3])));
        if (!__all(tpart <= m[f] + 11.5416f)) {   // 8 * log2(e)
          float tmax = fmaxf(tpart, __shfl_xor(tpart, 16));
          tmax = fmaxf(tmax, __shfl_xor(tmax, 32));
          float mnew = fmaxf(m[f], tmax);
          float alpha = exp2f(m[f] - mnew);
          m[f] = mnew;
          lsum[f] *= alpha;
          float a0 = __shfl(alpha, grp * 4 + 0);
          float a1 = __shfl(alpha, grp * 4 + 1);
          float a2 = __shfl(alpha, grp * 4 + 2);
          float a3 = __shfl(alpha, grp * 4 + 3);
          #pragma unroll
          for (int v = 0; v < 8; v++) {
            o_acc[f][v][0] *= a0; o_acc[f][v][1] *= a1;
            o_acc[f][v][2] *= a2; o_acc[f][v][3] *= a3;
          }
        }
        float p00 = exp2f(st[f][0][0] - m[f]), p01 = exp2f(st[f][0][1] - m[f]);
        float p02 = exp2f(st[f][0][2] - m[f]), p03 = exp2f(st[f][0][3] - m[f]);
        float p10 = exp2f(st[f][1][0] - m[f]), p11 = exp2f(st[f][1][1] - m[f]);
        float p12 = exp2f(st[f][1][2] - m[f]), p13 = exp2f(st[f][1][3] - m[f]);
        lsum[f] += ((p00 + p01) + (p02 + p03)) + ((p10 + p11) + (p12 + p13));
        union { unsigned int u[4]; short8 s8; } pu;
        pu.u[0] = pack_bf16(p00, p01);
        pu.u[1] = pack_bf16(p02, p03);
        pu.u[2] = pack_bf16(p10, p11);
        pu.u[3] = pack_bf16(p12, p13);
        short8 pa = pu.s8;
        __builtin_amdgcn_s_setprio(1);
        #pragma unroll
        for (int v = 0; v < 8; v++)
          o_acc[f][v] = __builtin_amdgcn_mfma_f32_16x16x32_bf16(pa, vf[v], o_acc[f][v], 0, 0, 0);
        __builtin_amdgcn_s_setprio(0);
      }
    }
  }

  #pragma unroll
  for (int f = 0; f < 2; f++) {
    float ls = lsum[f];
    ls += __shfl_xor(ls, 16);
    ls += __shfl_xor(ls, 32);
    float linv = 1.f / ls;
    float l0 = __shfl(linv, grp * 4 + 0);
    float l1 = __shfl(linv, grp * 4 + 1);
    float l2 = __shfl(linv, grp * 4 + 2);
    float l3 = __shfl(linv, grp * 4 + 3);
    const int qb = qb_[f];
    #pragma unroll
    for (int v = 0; v < 8; v++) {
      int col = h * 128 + v * 16 + lq;
      Obf[(size_t)(qb + grp * 4 + 0) * 2048 + col] = __float2bfloat16(o_acc[f][v][0] * l0);
      Obf[(size_t)(qb + grp * 4 + 1) * 2048 + col] = __float2bfloat16(o_acc[f][v][1] * l1);
      Obf[(size_t)(qb + grp * 4 + 2) * 2048 + col] = __float2bfloat16(o_acc[f][v][2] * l2);
      Obf[(size_t)(qb + grp * 4 + 3) * 2048 + col] = __float2bfloat16(o_acc[f][v][3] * l3);
    }
  }
}

// ================================================================ launch
extern "C" void kernel_launch(void* const* d_in, const int* in_sizes, int n_in,
                              void* d_out, int out_size, void* d_ws, size_t ws_size,
                              hipStream_t stream)
{
  (void)in_sizes; (void)n_in; (void)out_size; (void)ws_size;
  const float* x     = (const float*)d_in[0];
  const float* Wqa   = (const float*)d_in[1];
  const float* qlnw  = (const float*)d_in[2];
  const float* Wqb   = (const float*)d_in[3];
  const float* Wkva  = (const float*)d_in[4];
  const float* kvlnw = (const float*)d_in[5];
  const float* Wkvb  = (const float*)d_in[6];
  const float* Wo    = (const float*)d_in[7];
  float* out = (float*)d_out;
  char* ws = (char*)d_ws;

  size_t off = 0;
  auto take = [&](size_t bytes) {
    char* p = ws + off;
    off += (bytes + 255) & ~(size_t)255;
    return p;
  };

  __hip_bfloat16* x_bf   = (__hip_bfloat16*)take((size_t)4096 * 2048 * 2);
  __hip_bfloat16* WdownT = (__hip_bfloat16*)take((size_t)2176 * 2048 * 2);  // [WqaT;WkvaT]
  __hip_bfloat16* WqbT   = (__hip_bfloat16*)take((size_t)3072 * 1536 * 2);
  __hip_bfloat16* WkvbT  = (__hip_bfloat16*)take((size_t)4096 * 512 * 2);
  __hip_bfloat16* WoT    = (__hip_bfloat16*)take((size_t)2048 * 2048 * 2);
  char* regA             = take((size_t)4096 * 1536 * 4);  // q_lat (f32) -> Qh (bf16)
  float* kv              = (float*)take((size_t)4096 * 640 * 4);
  __hip_bfloat16* q_ln   = (__hip_bfloat16*)take((size_t)4096 * 1536 * 2);
  __hip_bfloat16* kv_ln  = (__hip_bfloat16*)take((size_t)4096 * 512 * 2);
  float* cs_tab          = (float*)take((size_t)4096 * 32 * 4);
  float* sn_tab          = (float*)take((size_t)4096 * 32 * 4);
  __hip_bfloat16* Khp    = (__hip_bfloat16*)take((size_t)16 * 4096 * 192 * 2);
  __hip_bfloat16* Vtp    = (__hip_bfloat16*)take((size_t)16 * 128 * 4096 * 2);
  __hip_bfloat16* o_bf   = (__hip_bfloat16*)take((size_t)4096 * 2048 * 2);

  float* q_lat = (float*)regA;
  __hip_bfloat16* Qh = (__hip_bfloat16*)regA;   // reuse after rmsnorm consumes q_lat

  // 1. cast x + rope table + transpose(Wqa,Wkva)
  cast_tr_kernel<<<dim3(12544), 256, 0, stream>>>(x, x_bf, Wqa, Wkva, WdownT,
                                                  cs_tab, sn_tab);

  // 2. gemm_down (first 544 blocks) + transpose(Wqb,Wkvb,Wo) backfill
  gemm_down_tr_kernel<<<dim3(11296), 256, 0, stream>>>(
      x_bf, WdownT, q_lat, kv, Wqb, Wkvb, Wo, WqbT, WkvbT, WoT);

  // 3. merged norms + rope-K broadcast
  rmsnorm2_kernel<<<dim3(8192), 256, 0, stream>>>(q_lat, kv, qlnw, kvlnw, q_ln, kv_ln,
                                                  cs_tab, sn_tab, Khp);

  // 4. fused up-projections (256^2, separate launches)
  gemm256_qup_kernel<<<dim3(12, 16), 512, 0, stream>>>(q_ln, WqbT, Qh, cs_tab, sn_tab, 1536);
  gemm256_kvup_kernel<<<dim3(16, 16), 512, 0, stream>>>(kv_ln, WkvbT, Khp, Vtp, 512);

  // 5. attention (pair-balanced, head-grouped per XCD, K+V LDS double-buffered)
  flash_attn_kernel<<<dim3(512), 256, 0, stream>>>(Qh, Khp, Vtp, o_bf);

  // 6. output projection (128^2, 512 blocks = 2/CU) -> d_out (f32)
  gemm_bt_kernel<<<dim3(16, 32), 256, 0, stream>>>(o_bf, WoT, out, 4096, 2048, 2048);
}

// Round 14
// 424.100 us; speedup vs baseline: 1.0495x; 1.0072x over previous
//
#include <hip/hip_runtime.h>
#include <hip/hip_bf16.h>

typedef __attribute__((ext_vector_type(8))) short short8;
typedef __attribute__((ext_vector_type(4))) float f32x4;

#define GLDS16(gp, lp)                                                         \
  __builtin_amdgcn_global_load_lds(                                            \
      (const __attribute__((address_space(1))) void*)(gp),                     \
      (__attribute__((address_space(3))) void*)(lp), 16, 0, 0)

static __device__ __forceinline__ unsigned int pack_bf16(float a, float b) {
  __hip_bfloat16 ba = __float2bfloat16(a), bb = __float2bfloat16(b);
  unsigned short ua = *reinterpret_cast<unsigned short*>(&ba);
  unsigned short ub = *reinterpret_cast<unsigned short*>(&bb);
  return (unsigned int)ua | ((unsigned int)ub << 16);
}

// XCD-contiguous remap of a linear block id (requires nwg % 8 == 0)
static __device__ __forceinline__ int xcd_swz(int linear, int nwg) {
  return (linear & 7) * (nwg >> 3) + (linear >> 3);
}

// ---------------- dispatch 1: cast x->bf16 + rope table + transpose(Wqa,Wkva)
__global__ __launch_bounds__(256) void cast_tr_kernel(
    const float* __restrict__ x, __hip_bfloat16* __restrict__ x_bf,
    const float* __restrict__ Wqa, const float* __restrict__ Wkva,
    __hip_bfloat16* __restrict__ WdownT,
    float* __restrict__ cs, float* __restrict__ sn)
{
  __shared__ float tile[32][33];
  int b = blockIdx.x;
  const int tid = threadIdx.x;
  if (b < 8192) {
    int i = b * 256 + tid;
    float4 v = ((const float4*)x)[i];
    x_bf[(size_t)i * 4 + 0] = __float2bfloat16(v.x);
    x_bf[(size_t)i * 4 + 1] = __float2bfloat16(v.y);
    x_bf[(size_t)i * 4 + 2] = __float2bfloat16(v.z);
    x_bf[(size_t)i * 4 + 3] = __float2bfloat16(v.w);
    if (b < 4096 && tid < 32) {
      float freq = powf(10000.f, -2.f * (float)tid / 64.f);
      float ang = (float)b * freq;
      cs[b * 32 + tid] = cosf(ang);
      sn[b * 32 + tid] = sinf(ang);
    }
    return;
  }
  b -= 8192;
  const float* in;
  __hip_bfloat16* outp;
  int K, N, Npad, gx;
  if (b < 3072) { in = Wqa;  outp = WdownT;                        K = 2048; N = 1536; Npad = 1536; gx = 48; }
  else { b -= 3072; in = Wkva; outp = WdownT + (size_t)1536 * 2048; K = 2048; N = 576;  Npad = 640;  gx = 20; }
  int n0 = (b % gx) * 32, k0 = (b / gx) * 32;
  int tx = tid & 31, ty = tid >> 5;
  #pragma unroll
  for (int i = ty; i < 32; i += 8) {
    int k = k0 + i, n = n0 + tx;
    tile[i][tx] = (n < N) ? in[(size_t)k * N + n] : 0.f;
  }
  __syncthreads();
  #pragma unroll
  for (int i = ty; i < 32; i += 8) {
    int n = n0 + i, k = k0 + tx;
    if (n < Npad) outp[(size_t)n * K + k] = __float2bfloat16(tile[tx][i]);
  }
}

// ================================================================ 128^2 GEMM core
// assumes: tid, As, Bs (bf16 ptrs), row0, col0 already defined
#define GEMM128_CORE(A, BT, Kdim)                                              \
  const int wave = tid >> 6, lane = tid & 63;                                  \
  const int wr = wave >> 1, wc = wave & 1;                                     \
  const int lq = lane & 15, grp = lane >> 4;                                   \
  const f32x4 z4 = {0.f, 0.f, 0.f, 0.f};                                       \
  f32x4 acc[4][4];                                                             \
  _Pragma("unroll") for (int i = 0; i < 4; i++)                                \
      _Pragma("unroll") for (int j = 0; j < 4; j++) acc[i][j] = z4;            \
  for (int k0 = 0; k0 < (Kdim); k0 += 32) {                                    \
    _Pragma("unroll") for (int i = 0; i < 2; i++) {                            \
      const int t = wave + 4 * i;                                              \
      const int c = t * 64 + lane;                                             \
      const int cr = c >> 2;                                                   \
      const int ko = (c & 3) << 3;                                             \
      GLDS16((A) + (size_t)(row0 + cr) * (Kdim) + (k0 + ko), (char*)As + t * 1024); \
      GLDS16((BT) + (size_t)(col0 + cr) * (Kdim) + (k0 + ko), (char*)Bs + t * 1024);\
    }                                                                          \
    __syncthreads();                                                           \
    short8 af[4], bfr[4];                                                      \
    _Pragma("unroll") for (int mm = 0; mm < 4; mm++)                           \
      af[mm] = *(const short8*)((const short*)As + ((wr * 64 + mm * 16 + lq) * 32 + grp * 8)); \
    _Pragma("unroll") for (int nn = 0; nn < 4; nn++)                           \
      bfr[nn] = *(const short8*)((const short*)Bs + ((wc * 64 + nn * 16 + lq) * 32 + grp * 8));\
    _Pragma("unroll") for (int mm = 0; mm < 4; mm++)                           \
      _Pragma("unroll") for (int nn = 0; nn < 4; nn++)                         \
        acc[mm][nn] = __builtin_amdgcn_mfma_f32_16x16x32_bf16(af[mm], bfr[nn], acc[mm][nn], 0, 0, 0); \
    __syncthreads();                                                           \
  }

// ---------------------------------------------------------------- plain 128^2 GEMM
__global__ __launch_bounds__(256) void gemm_bt_kernel(
    const __hip_bfloat16* __restrict__ A,
    const __hip_bfloat16* __restrict__ BT,
    float* __restrict__ C, int M, int N, int K)
{
  __shared__ __hip_bfloat16 As[128 * 32];
  __shared__ __hip_bfloat16 Bs[128 * 32];
  const int tid = threadIdx.x;
  const int nwg = gridDim.x * gridDim.y;
  const int orig = xcd_swz(blockIdx.y * gridDim.x + blockIdx.x, nwg);
  const int row0 = (orig / gridDim.x) * 128;
  const int col0 = (orig % gridDim.x) * 128;
  GEMM128_CORE(A, BT, K)
  (void)M;
  #pragma unroll
  for (int mm = 0; mm < 4; mm++)
    #pragma unroll
    for (int nn = 0; nn < 4; nn++) {
      const int row = row0 + wr * 64 + mm * 16 + grp * 4;
      const int col = col0 + wc * 64 + nn * 16 + lq;
      float* Cp = C + (size_t)row * N + col;
      #pragma unroll
      for (int rr = 0; rr < 4; rr++) Cp[(size_t)rr * N] = acc[mm][nn][rr];
    }
}

// ---------------- dispatch 2: gemm_down (blocks 0..543, issued first) +
// transpose(Wqb,Wkvb,Wo) backfill (blocks 544..11295). Shared 16.5KB LDS union.
__global__ __launch_bounds__(256) void gemm_down_tr_kernel(
    const __hip_bfloat16* __restrict__ A,
    const __hip_bfloat16* __restrict__ BT,
    float* __restrict__ q_lat, float* __restrict__ kvout,
    const float* __restrict__ Wqb, const float* __restrict__ Wkvb,
    const float* __restrict__ Wo,
    __hip_bfloat16* __restrict__ WqbT, __hip_bfloat16* __restrict__ WkvbT,
    __hip_bfloat16* __restrict__ WoT)
{
  __shared__ __align__(16) char smem[16512];
  const int tid = threadIdx.x;
  int b = blockIdx.x;
  if (b < 544) {
    __hip_bfloat16* As = (__hip_bfloat16*)smem;
    __hip_bfloat16* Bs = (__hip_bfloat16*)(smem + 8192);
    const int orig = xcd_swz(b, 544);
    const int row0 = (orig / 17) * 128;
    const int col0 = (orig % 17) * 128;
    GEMM128_CORE(A, BT, 2048)
    #pragma unroll
    for (int mm = 0; mm < 4; mm++)
      #pragma unroll
      for (int nn = 0; nn < 4; nn++) {
        const int row = row0 + wr * 64 + mm * 16 + grp * 4;
        const int col = col0 + wc * 64 + nn * 16 + lq;
        float* Cp = (col < 1536) ? (q_lat + (size_t)row * 1536 + col)
                                 : (kvout + (size_t)row * 640 + (col - 1536));
        const size_t ld = (col < 1536) ? 1536 : 640;
        #pragma unroll
        for (int rr = 0; rr < 4; rr++) Cp[(size_t)rr * ld] = acc[mm][nn][rr];
      }
    return;
  }
  b -= 544;
  float (*tile)[33] = (float(*)[33])smem;
  const float* in;
  __hip_bfloat16* outp;
  int K, N, Npad, gx;
  if (b < 4608)      { in = Wqb;  outp = WqbT;  K = 1536; N = 3072; Npad = 3072; gx = 96; }
  else if (b < 6656) { b -= 4608; in = Wkvb; outp = WkvbT; K = 512;  N = 4096; Npad = 4096; gx = 128; }
  else               { b -= 6656; in = Wo;   outp = WoT;   K = 2048; N = 2048; Npad = 2048; gx = 64; }
  int n0 = (b % gx) * 32, k0 = (b / gx) * 32;
  int tx = tid & 31, ty = tid >> 5;
  #pragma unroll
  for (int i = ty; i < 32; i += 8) {
    int k = k0 + i, n = n0 + tx;
    tile[i][tx] = (n < N) ? in[(size_t)k * N + n] : 0.f;
  }
  __syncthreads();
  #pragma unroll
  for (int i = ty; i < 32; i += 8) {
    int n = n0 + i, k = k0 + tx;
    if (n < Npad) outp[(size_t)n * K + k] = __float2bfloat16(tile[tx][i]);
  }
}

// ================================================================ 256^2 GEMM core
// BK=64, 8 waves, double-buffered 128KB LDS, XOR-swizzle, counted vmcnt(8).
#define GEMM256_MAIN(Aptr, BTptr, Kdim)                                        \
  __shared__ __align__(16) char Ab[2][32768];                                  \
  __shared__ __align__(16) char Bb[2][32768];                                  \
  const int tid = threadIdx.x;                                                 \
  const int wid = tid >> 6, lane = tid & 63;                                   \
  const int wm = wid >> 2, wn = wid & 3;                                       \
  const int lq = lane & 15, grp = lane >> 4;                                   \
  const int nwg = gridDim.x * gridDim.y;                                       \
  const int orig = xcd_swz(blockIdx.y * gridDim.x + blockIdx.x, nwg);          \
  const int row0 = (orig / gridDim.x) * 256;                                   \
  const int col0 = (orig % gridDim.x) * 256;                                   \
  const size_t K2 = (size_t)(Kdim) * 2;                                        \
  const char* pa[4]; const char* pb[4]; int ldst[4];                           \
  _Pragma("unroll") for (int i = 0; i < 4; i++) {                              \
    int L = i * 8192 + tid * 16;                                               \
    int r = L >> 7;                                                            \
    int csw = (L & 127) ^ ((r & 7) << 4);                                      \
    ldst[i] = L;                                                               \
    pa[i] = (const char*)(Aptr) + (size_t)(row0 + r) * K2 + csw;               \
    pb[i] = (const char*)(BTptr) + (size_t)(col0 + r) * K2 + csw;              \
  }                                                                            \
  const int xm = (lq & 7) << 4;                                                \
  const f32x4 z4 = {0.f, 0.f, 0.f, 0.f};                                       \
  f32x4 acc[8][4];                                                             \
  _Pragma("unroll") for (int i = 0; i < 8; i++)                                \
    _Pragma("unroll") for (int j = 0; j < 4; j++) acc[i][j] = z4;              \
  const int nt = (Kdim) >> 6;                                                  \
  _Pragma("unroll") for (int i = 0; i < 4; i++) {                              \
    GLDS16(pa[i], &Ab[0][0] + ldst[i]);                                        \
    GLDS16(pb[i], &Bb[0][0] + ldst[i]);                                        \
  }                                                                            \
  for (int t = 0; t < nt; ++t) {                                               \
    const int b = t & 1;                                                       \
    if (t + 1 < nt) {                                                          \
      const size_t koff = (size_t)(t + 1) * 128;                               \
      _Pragma("unroll") for (int i = 0; i < 4; i++) {                          \
        GLDS16(pa[i] + koff, &Ab[b ^ 1][0] + ldst[i]);                         \
        GLDS16(pb[i] + koff, &Bb[b ^ 1][0] + ldst[i]);                         \
      }                                                                        \
      asm volatile("s_waitcnt vmcnt(8)" ::: "memory");                         \
    } else {                                                                   \
      asm volatile("s_waitcnt vmcnt(0)" ::: "memory");                         \
    }                                                                          \
    __builtin_amdgcn_sched_barrier(0);                                         \
    __builtin_amdgcn_s_barrier();                                              \
    __builtin_amdgcn_sched_barrier(0);                                         \
    const char* Ar = &Ab[b][0];                                                \
    const char* Br = &Bb[b][0];                                                \
    short8 bfr[4][2];                                                          \
    _Pragma("unroll") for (int n = 0; n < 4; n++)                              \
      _Pragma("unroll") for (int ks = 0; ks < 2; ks++)                         \
        bfr[n][ks] = *(const short8*)(Br + (wn * 64 + n * 16 + lq) * 128 +     \
                                      ((ks * 64 + grp * 16) ^ xm));            \
    _Pragma("unroll") for (int mh = 0; mh < 4; mh++) {                         \
      short8 af[2][2];                                                         \
      _Pragma("unroll") for (int mi = 0; mi < 2; mi++)                         \
        _Pragma("unroll") for (int ks = 0; ks < 2; ks++)                       \
          af[mi][ks] = *(const short8*)(Ar + (wm * 128 + (mh * 2 + mi) * 16 + lq) * 128 + \
                                        ((ks * 64 + grp * 16) ^ xm));          \
      __builtin_amdgcn_s_setprio(1);                                           \
      _Pragma("unroll") for (int mi = 0; mi < 2; mi++)                         \
        _Pragma("unroll") for (int n = 0; n < 4; n++)                          \
          _Pragma("unroll") for (int ks = 0; ks < 2; ks++)                     \
            acc[mh * 2 + mi][n] = __builtin_amdgcn_mfma_f32_16x16x32_bf16(     \
                af[mi][ks], bfr[n][ks], acc[mh * 2 + mi][n], 0, 0, 0);         \
      __builtin_amdgcn_s_setprio(0);                                           \
    }                                                                          \
    __builtin_amdgcn_sched_barrier(0);                                         \
    __builtin_amdgcn_s_barrier();                                              \
    __builtin_amdgcn_sched_barrier(0);                                         \
  }

// ------------------------------- fused Q-up GEMM (256^2): rope+scale -> Qh bf16
__global__ __launch_bounds__(512, 2) void gemm256_qup_kernel(
    const __hip_bfloat16* __restrict__ A,
    const __hip_bfloat16* __restrict__ BT,
    __hip_bfloat16* __restrict__ Qh,
    const float* __restrict__ cs_tab, const float* __restrict__ sn_tab, int K)
{
  GEMM256_MAIN(A, BT, K)
  const float scale = 0.10411654209f;  // (1/sqrt(192)) * log2(e)
  #pragma unroll
  for (int m = 0; m < 8; m++)
    #pragma unroll
    for (int n = 0; n < 4; n++) {
      const int col = col0 + wn * 64 + n * 16 + lq;
      const int h = col / 192;
      const int d = col - h * 192;
      const bool is_rope = (d >= 128);     // uniform per 16-col segment
      const int i = (d - 128) >> 1;
      const float sgn = (d & 1) ? 1.f : -1.f;
      #pragma unroll
      for (int rr = 0; rr < 4; rr++) {
        const int t = row0 + wm * 128 + m * 16 + grp * 4 + rr;
        float val = acc[m][n][rr];
        float partner = __shfl_xor(val, 1);
        float outv = val;
        if (is_rope) {
          float c = cs_tab[t * 32 + i];
          float s = sn_tab[t * 32 + i];
          outv = val * c + sgn * partner * s;
        }
        Qh[((size_t)h * 4096 + t) * 192 + d] = __float2bfloat16(outv * scale);
      }
    }
}

// ------------------------------- fused KV-up GEMM (256^2): K-nope + V^T
__global__ __launch_bounds__(512, 2) void gemm256_kvup_kernel(
    const __hip_bfloat16* __restrict__ A,
    const __hip_bfloat16* __restrict__ BT,
    __hip_bfloat16* __restrict__ Kh,
    __hip_bfloat16* __restrict__ Vt, int K)
{
  GEMM256_MAIN(A, BT, K)
  #pragma unroll
  for (int m = 0; m < 8; m++)
    #pragma unroll
    for (int n = 0; n < 4; n++) {
      const int col = col0 + wn * 64 + n * 16 + lq;
      const int h = col >> 8;
      const int j = col & 255;
      const int t0 = row0 + wm * 128 + m * 16 + grp * 4;
      if (j < 128) {                       // uniform per 16-col segment
        #pragma unroll
        for (int rr = 0; rr < 4; rr++)
          Kh[((size_t)h * 4096 + t0 + rr) * 192 + j] = __float2bfloat16(acc[m][n][rr]);
      } else {
        const int vd = j - 128;
        uint2 w;
        w.x = pack_bf16(acc[m][n][0], acc[m][n][1]);
        w.y = pack_bf16(acc[m][n][2], acc[m][n][3]);
        *(uint2*)(Vt + ((size_t)h * 128 + vd) * 4096 + t0) = w;
      }
    }
}

// --------------- merged RMSNorm (q rows 0..4095, kv rows 4096..8191) + rope-K
__global__ __launch_bounds__(256) void rmsnorm2_kernel(
    const float* __restrict__ q_lat, const float* __restrict__ kv,
    const float* __restrict__ qw, const float* __restrict__ kvw,
    __hip_bfloat16* __restrict__ q_ln, __hip_bfloat16* __restrict__ kv_ln,
    const float* __restrict__ cs_tab, const float* __restrict__ sn_tab,
    __hip_bfloat16* __restrict__ Kh)
{
  const int b = blockIdx.x;
  const bool isq = (b < 4096);
  const int row = isq ? b : b - 4096;
  const int ld = isq ? 1536 : 640;
  const int W = isq ? 1536 : 512;
  const float* x = (isq ? q_lat : kv) + (size_t)row * ld;
  const float* w = isq ? qw : kvw;
  __hip_bfloat16* out = (isq ? q_ln : kv_ln) + (size_t)row * W;
  const int tid = threadIdx.x;
  const int wave = tid >> 6, lane = tid & 63;
  float ss = 0.f;
  for (int i = tid; i < W; i += 256) { float v = x[i]; ss += v * v; }
  #pragma unroll
  for (int o = 32; o; o >>= 1) ss += __shfl_xor(ss, o);
  __shared__ float red[4];
  __shared__ float stot;
  if (lane == 0) red[wave] = ss;
  __syncthreads();
  if (tid == 0) stot = red[0] + red[1] + red[2] + red[3];
  __syncthreads();
  const float rstd = rsqrtf(stot / (float)W + 1.1920929e-7f);
  for (int i = tid; i < W; i += 256)
    out[i] = __float2bfloat16(x[i] * rstd * w[i]);
  if (!isq) {
    const int t = row;
    for (int e = tid; e < 512; e += 256) {
      int h = e >> 5, i = e & 31;
      float c = cs_tab[t * 32 + i], s = sn_tab[t * 32 + i];
      float xe = x[512 + 2 * i];
      float xo = x[512 + 2 * i + 1];
      size_t base = ((size_t)h * 4096 + t) * 192 + 128 + 2 * i;
      Kh[base]     = __float2bfloat16(xe * c - xo * s);
      Kh[base + 1] = __float2bfloat16(xo * c + xe * s);
    }
  }
}

// ---------------------------------------------------------------- flash attention
// K+V staged in LDS (64-key tiles, double-buffered, pre-swizzled source).
// Pair-balanced causal tiling; each XCD hosts 2 heads (K/V L2-resident).
// K rows permuted at QK so P lands directly in the PV A-fragment layout.
// exp2-domain softmax; lane-partial defer-max; lsum computed ON THE MATRIX
// PIPE via a 9th ones-column PV MFMA (row-sums land per-lane, rescaled by
// alpha with o_acc automatically; no psum adds, no epilogue shuffles).
__global__ __launch_bounds__(256, 2) void flash_attn_kernel(
    const __hip_bfloat16* __restrict__ Qh,
    const __hip_bfloat16* __restrict__ Kh,
    const __hip_bfloat16* __restrict__ Vt,
    __hip_bfloat16* __restrict__ Obf)
{
  __shared__ __align__(16) char Klds[2][24576];   // 64 keys x 384B, swizzled
  __shared__ __align__(16) char Vlds[2][16384];   // 128 vd x 128B, swizzled

  const int hw = blockIdx.x;
  const int rest = hw >> 3;
  const int h = (hw & 7) + 8 * (rest & 1);
  const int p = rest >> 1;                        // pair index 0..31

  const int wave = threadIdx.x >> 6;
  const int lane = threadIdx.x & 63;
  const int lq = lane & 15;
  const int grp = lane >> 4;
  const int qb_[2] = {(63 - p) * 64 + wave * 16,  // f=0: heavy rows
                      p * 64 + wave * 16};        // f=1: light rows
  const int kendA = qb_[0] + 16;
  const int kendB = qb_[1] + 16;
  const int nt = 64 - p;

  const char* Kh_ = (const char*)(Kh + (size_t)h * 4096 * 192);
  const char* Vh_ = (const char*)(Vt + (size_t)h * 128 * 4096);
  const short* Qh_ = (const short*)Qh + (size_t)h * 4096 * 192;

  int kbase[6], vbase[4];
  #pragma unroll
  for (int i = 0; i < 6; i++) {
    int L = (wave * 6 + i) * 1024 + lane * 16;
    int r = L / 384, c = L - r * 384;
    int swb = (r & 3) | (((r >> 3) & 1) << 2);
    kbase[i] = r * 384 + (c ^ (swb << 4));
  }
  #pragma unroll
  for (int i = 0; i < 4; i++) {
    int L = (wave * 4 + i) * 1024 + lane * 16;
    int r = L >> 7, c = L & 127;
    vbase[i] = r * 8192 + (c ^ ((r & 7) << 4));
  }

  short8 qf[2][6];
  #pragma unroll
  for (int f = 0; f < 2; f++)
    #pragma unroll
    for (int d = 0; d < 6; d++)
      qf[f][d] = *(const short8*)(Qh_ + (size_t)(qb_[f] + lq) * 192 + d * 32 + grp * 8);

  // ones B-fragment (bf16 1.0 packed) for the lsum column
  union { unsigned int u[4]; short8 s8; } ones_u;
  ones_u.u[0] = 0x3F803F80u; ones_u.u[1] = 0x3F803F80u;
  ones_u.u[2] = 0x3F803F80u; ones_u.u[3] = 0x3F803F80u;
  const short8 vf_ones = ones_u.s8;

  const f32x4 z4 = {0.f, 0.f, 0.f, 0.f};
  f32x4 o_acc[2][9];                    // [..][8] = row-sum (lsum) column
  #pragma unroll
  for (int f = 0; f < 2; f++)
    #pragma unroll
    for (int v = 0; v < 9; v++) o_acc[f][v] = z4;
  float m[2] = {-1e30f, -1e30f};

  const int krow_l = ((lq >> 2) << 3) + (lq & 3);            // + h2*32 + kt*4
  const int kxm = ((lq & 3) | (((lq >> 2) & 1) << 2)) << 4;  // K swizzle mask
  const int vxm = (lq & 7) << 4;                             // V swizzle mask

  // stage tile 0
  {
    #pragma unroll
    for (int i = 0; i < 6; i++) GLDS16(Kh_ + kbase[i], Klds[0] + (wave * 6 + i) * 1024);
    #pragma unroll
    for (int i = 0; i < 4; i++) GLDS16(Vh_ + vbase[i], Vlds[0] + (wave * 4 + i) * 1024);
  }

  for (int t = 0; t < nt; t++) {
    __syncthreads();  // stage t complete for all waves
    if (t + 1 < nt) {
      const char* Kp = Kh_ + (size_t)(t + 1) * 64 * 384;
      const char* Vp = Vh_ + (size_t)(t + 1) * 128;
      char* Kd = Klds[(t + 1) & 1];
      char* Vd = Vlds[(t + 1) & 1];
      #pragma unroll
      for (int i = 0; i < 6; i++) GLDS16(Kp + kbase[i], Kd + (wave * 6 + i) * 1024);
      #pragma unroll
      for (int i = 0; i < 4; i++) GLDS16(Vp + vbase[i], Vd + (wave * 4 + i) * 1024);
    }
    const char* Kb = Klds[t & 1];
    const char* Vb = Vlds[t & 1];
    const int ks = t * 64;

    #pragma unroll
    for (int h2 = 0; h2 < 2; h2++) {
      const int ks32 = ks + h2 * 32;
      if (ks32 >= kendA) continue;          // wave-uniform
      const bool act1 = (ks32 < kendB);     // wave-uniform

      f32x4 st[2][2];  // [f][kt]
      #pragma unroll
      for (int kt = 0; kt < 2; kt++) {
        const int row = h2 * 32 + krow_l + kt * 4;
        short8 kf[6];
        #pragma unroll
        for (int d = 0; d < 6; d++)
          kf[d] = *(const short8*)(Kb + row * 384 + ((d * 64 + grp * 16) ^ kxm));
        __builtin_amdgcn_s_setprio(1);
        #pragma unroll
        for (int f = 0; f < 2; f++) {
          if (f == 1 && !act1) continue;
          f32x4 acc = z4;
          #pragma unroll
          for (int d = 0; d < 6; d++)
            acc = __builtin_amdgcn_mfma_f32_16x16x32_bf16(kf[d], qf[f][d], acc, 0, 0, 0);
          st[f][kt] = acc;
        }
        __builtin_amdgcn_s_setprio(0);
      }

      short8 vf[8];
      #pragma unroll
      for (int v = 0; v < 8; v++)
        vf[v] = *(const short8*)(Vb + (v * 16 + lq) * 128 + ((h2 * 64 + grp * 16) ^ vxm));

      #pragma unroll
      for (int f = 0; f < 2; f++) {
        if (f == 1 && !act1) continue;
        const int qg = qb_[f] + lq;
        const bool need_mask = (ks32 + 31 > qb_[f]);
        if (need_mask) {
          #pragma unroll
          for (int kt = 0; kt < 2; kt++)
            #pragma unroll
            for (int r = 0; r < 4; r++) {
              int key = ks32 + grp * 8 + kt * 4 + r;
              if (key > qg) st[f][kt][r] = -1e30f;
            }
        }
        // lane-partial defer-max: shuffle reduce only when the rescale fires
        float tpart = fmaxf(fmaxf(fmaxf(st[f][0][0], st[f][0][1]), fmaxf(st[f][0][2], st[f][0][3])),
                            fmaxf(fmaxf(st[f][1][0], st[f][1][1]), fmaxf(st[f][1][2], st[f][1][3])));
        if (!__all(tpart <= m[f] + 11.5416f)) {   // 8 * log2(e)
          float tmax = fmaxf(tpart, __shfl_xor(tpart, 16));
          tmax = fmaxf(tmax, __shfl_xor(tmax, 32));
          float mnew = fmaxf(m[f], tmax);
          float alpha = exp2f(m[f] - mnew);
          m[f] = mnew;
          float a0 = __shfl(alpha, grp * 4 + 0);
          float a1 = __shfl(alpha, grp * 4 + 1);
          float a2 = __shfl(alpha, grp * 4 + 2);
          float a3 = __shfl(alpha, grp * 4 + 3);
          #pragma unroll
          for (int v = 0; v < 9; v++) {      // lsum column rescales with O
            o_acc[f][v][0] *= a0; o_acc[f][v][1] *= a1;
            o_acc[f][v][2] *= a2; o_acc[f][v][3] *= a3;
          }
        }
        float p00 = exp2f(st[f][0][0] - m[f]), p01 = exp2f(st[f][0][1] - m[f]);
        float p02 = exp2f(st[f][0][2] - m[f]), p03 = exp2f(st[f][0][3] - m[f]);
        float p10 = exp2f(st[f][1][0] - m[f]), p11 = exp2f(st[f][1][1] - m[f]);
        float p12 = exp2f(st[f][1][2] - m[f]), p13 = exp2f(st[f][1][3] - m[f]);
        union { unsigned int u[4]; short8 s8; } pu;
        pu.u[0] = pack_bf16(p00, p01);
        pu.u[1] = pack_bf16(p02, p03);
        pu.u[2] = pack_bf16(p10, p11);
        pu.u[3] = pack_bf16(p12, p13);
        short8 pa = pu.s8;
        __builtin_amdgcn_s_setprio(1);
        #pragma unroll
        for (int v = 0; v < 8; v++)
          o_acc[f][v] = __builtin_amdgcn_mfma_f32_16x16x32_bf16(pa, vf[v], o_acc[f][v], 0, 0, 0);
        o_acc[f][8] = __builtin_amdgcn_mfma_f32_16x16x32_bf16(pa, vf_ones, o_acc[f][8], 0, 0, 0);
        __builtin_amdgcn_s_setprio(0);
      }
    }
  }

  #pragma unroll
  for (int f = 0; f < 2; f++) {
    // per-lane denominators: o_acc[f][8][rr] = lsum of row qb+grp*4+rr
    float l0 = 1.f / o_acc[f][8][0];
    float l1 = 1.f / o_acc[f][8][1];
    float l2 = 1.f / o_acc[f][8][2];
    float l3 = 1.f / o_acc[f][8][3];
    const int qb = qb_[f];
    #pragma unroll
    for (int v = 0; v < 8; v++) {
      int col = h * 128 + v * 16 + lq;
      Obf[(size_t)(qb + grp * 4 + 0) * 2048 + col] = __float2bfloat16(o_acc[f][v][0] * l0);
      Obf[(size_t)(qb + grp * 4 + 1) * 2048 + col] = __float2bfloat16(o_acc[f][v][1] * l1);
      Obf[(size_t)(qb + grp * 4 + 2) * 2048 + col] = __float2bfloat16(o_acc[f][v][2] * l2);
      Obf[(size_t)(qb + grp * 4 + 3) * 2048 + col] = __float2bfloat16(o_acc[f][v][3] * l3);
    }
  }
}

// ================================================================ launch
extern "C" void kernel_launch(void* const* d_in, const int* in_sizes, int n_in,
                              void* d_out, int out_size, void* d_ws, size_t ws_size,
                              hipStream_t stream)
{
  (void)in_sizes; (void)n_in; (void)out_size; (void)ws_size;
  const float* x     = (const float*)d_in[0];
  const float* Wqa   = (const float*)d_in[1];
  const float* qlnw  = (const float*)d_in[2];
  const float* Wqb   = (const float*)d_in[3];
  const float* Wkva  = (const float*)d_in[4];
  const float* kvlnw = (const float*)d_in[5];
  const float* Wkvb  = (const float*)d_in[6];
  const float* Wo    = (const float*)d_in[7];
  float* out = (float*)d_out;
  char* ws = (char*)d_ws;

  size_t off = 0;
  auto take = [&](size_t bytes) {
    char* p = ws + off;
    off += (bytes + 255) & ~(size_t)255;
    return p;
  };

  __hip_bfloat16* x_bf   = (__hip_bfloat16*)take((size_t)4096 * 2048 * 2);
  __hip_bfloat16* WdownT = (__hip_bfloat16*)take((size_t)2176 * 2048 * 2);  // [WqaT;WkvaT]
  __hip_bfloat16* WqbT   = (__hip_bfloat16*)take((size_t)3072 * 1536 * 2);
  __hip_bfloat16* WkvbT  = (__hip_bfloat16*)take((size_t)4096 * 512 * 2);
  __hip_bfloat16* WoT    = (__hip_bfloat16*)take((size_t)2048 * 2048 * 2);
  char* regA             = take((size_t)4096 * 1536 * 4);  // q_lat (f32) -> Qh (bf16)
  float* kv              = (float*)take((size_t)4096 * 640 * 4);
  __hip_bfloat16* q_ln   = (__hip_bfloat16*)take((size_t)4096 * 1536 * 2);
  __hip_bfloat16* kv_ln  = (__hip_bfloat16*)take((size_t)4096 * 512 * 2);
  float* cs_tab          = (float*)take((size_t)4096 * 32 * 4);
  float* sn_tab          = (float*)take((size_t)4096 * 32 * 4);
  __hip_bfloat16* Khp    = (__hip_bfloat16*)take((size_t)16 * 4096 * 192 * 2);
  __hip_bfloat16* Vtp    = (__hip_bfloat16*)take((size_t)16 * 128 * 4096 * 2);
  __hip_bfloat16* o_bf   = (__hip_bfloat16*)take((size_t)4096 * 2048 * 2);

  float* q_lat = (float*)regA;
  __hip_bfloat16* Qh = (__hip_bfloat16*)regA;   // reuse after rmsnorm consumes q_lat

  // 1. cast x + rope table + transpose(Wqa,Wkva)
  cast_tr_kernel<<<dim3(12544), 256, 0, stream>>>(x, x_bf, Wqa, Wkva, WdownT,
                                                  cs_tab, sn_tab);

  // 2. gemm_down (first 544 blocks) + transpose(Wqb,Wkvb,Wo) backfill
  gemm_down_tr_kernel<<<dim3(11296), 256, 0, stream>>>(
      x_bf, WdownT, q_lat, kv, Wqb, Wkvb, Wo, WqbT, WkvbT, WoT);

  // 3. merged norms + rope-K broadcast
  rmsnorm2_kernel<<<dim3(8192), 256, 0, stream>>>(q_lat, kv, qlnw, kvlnw, q_ln, kv_ln,
                                                  cs_tab, sn_tab, Khp);

  // 4. fused up-projections (256^2, separate launches)
  gemm256_qup_kernel<<<dim3(12, 16), 512, 0, stream>>>(q_ln, WqbT, Qh, cs_tab, sn_tab, 1536);
  gemm256_kvup_kernel<<<dim3(16, 16), 512, 0, stream>>>(kv_ln, WkvbT, Khp, Vtp, 512);

  // 5. attention (pair-balanced, head-grouped per XCD, K+V LDS double-buffered)
  flash_attn_kernel<<<dim3(512), 256, 0, stream>>>(Qh, Khp, Vtp, o_bf);

  // 6. output projection (128^2, 512 blocks = 2/CU) -> d_out (f32)
  gemm_bt_kernel<<<dim3(16, 32), 256, 0, stream>>>(o_bf, WoT, out, 4096, 2048, 2048);
}